// Round 1
// baseline (800.902 us; speedup 1.0000x reference)
//
#include <hip/hip_runtime.h>
#include <math.h>

#define NN    16384     // nodes
#define DIN   1024
#define HCdim 512       // H*C
#define NHEAD 4
#define NE_   262144    // edges (without self loops)
#define EP_   (NE_ + NN) // with self loops

__device__ __forceinline__ float eluf(float x){ return x > 0.f ? x : expm1f(x); }
__device__ __forceinline__ float lrelu(float x){ return x > 0.f ? x : 0.2f * x; }

// ---------------- CSR build ----------------
__global__ void k_zero_i(int* __restrict__ p, int n){
    int i = blockIdx.x * 256 + threadIdx.x;
    if (i < n) p[i] = 0;
}

__global__ void k_degree(const int* __restrict__ ei, int* __restrict__ deg){
    int i = blockIdx.x * 256 + threadIdx.x;
    if (i >= EP_) return;
    int d = (i < NE_) ? ei[NE_ + i] : (i - NE_);
    atomicAdd(&deg[d], 1);
}

__global__ __launch_bounds__(1024) void k_scan(const int* __restrict__ deg, int* __restrict__ offs){
    __shared__ int s[1024];
    int tid  = threadIdx.x;
    int base = tid * 16;
    int local[16];
    int sum = 0;
    #pragma unroll
    for (int i = 0; i < 16; i++){ local[i] = deg[base + i]; sum += local[i]; }
    s[tid] = sum;
    __syncthreads();
    for (int off = 1; off < 1024; off <<= 1){
        int v = (tid >= off) ? s[tid - off] : 0;
        __syncthreads();
        s[tid] += v;
        __syncthreads();
    }
    int run = (tid == 0) ? 0 : s[tid - 1];
    #pragma unroll
    for (int i = 0; i < 16; i++){ offs[base + i] = run; run += local[i]; }
    if (tid == 1023) offs[NN] = run;
}

__global__ void k_scatter(const int* __restrict__ ei, const int* __restrict__ offs,
                          int* __restrict__ cursor, int* __restrict__ csr){
    int i = blockIdx.x * 256 + threadIdx.x;
    if (i >= EP_) return;
    int srcv, dstv;
    if (i < NE_){ srcv = ei[i]; dstv = ei[NE_ + i]; }
    else        { srcv = dstv = i - NE_; }
    int pos = offs[dstv] + atomicAdd(&cursor[dstv], 1);
    csr[pos] = srcv;
}

// ---------------- fp32 tiled GEMM: C[M,Nn] = A[M,K] @ B[K,Nn] ----------------
__global__ __launch_bounds__(256) void gemm_fp32(const float* __restrict__ A,
                                                 const float* __restrict__ B,
                                                 float* __restrict__ C,
                                                 int M, int Nn, int K){
    __shared__ float As[16][68];   // [k][m], padded
    __shared__ float Bs[16][68];   // [k][n], padded
    int tid = threadIdx.x;
    int m0 = blockIdx.y * 64;
    int n0 = blockIdx.x * 64;
    int tx = tid & 15, ty = tid >> 4;
    int la_r = tid >> 2,  la_c = (tid & 3) << 2;   // A: 64 rows x 16 k
    int lb_r = tid >> 4,  lb_c = (tid & 15) << 2;  // B: 16 k x 64 n
    const float* Aptr = A + (size_t)(m0 + la_r) * K + la_c;
    const float* Bptr = B + (size_t)lb_r * Nn + n0 + lb_c;
    float acc[4][4] = {};
    for (int k0 = 0; k0 < K; k0 += 16){
        float4 av = *(const float4*)(Aptr + k0);
        float4 bv = *(const float4*)(Bptr + (size_t)k0 * Nn);
        __syncthreads();
        As[la_c + 0][la_r] = av.x;
        As[la_c + 1][la_r] = av.y;
        As[la_c + 2][la_r] = av.z;
        As[la_c + 3][la_r] = av.w;
        *(float4*)&Bs[lb_r][lb_c] = bv;
        __syncthreads();
        #pragma unroll
        for (int k = 0; k < 16; k++){
            float4 a4 = *(const float4*)&As[k][ty << 2];
            float4 b4 = *(const float4*)&Bs[k][tx << 2];
            float avv[4] = {a4.x, a4.y, a4.z, a4.w};
            float bvv[4] = {b4.x, b4.y, b4.z, b4.w};
            #pragma unroll
            for (int i = 0; i < 4; i++)
                #pragma unroll
                for (int j = 0; j < 4; j++)
                    acc[i][j] = fmaf(avv[i], bvv[j], acc[i][j]);
        }
    }
    #pragma unroll
    for (int i = 0; i < 4; i++){
        float4 o = {acc[i][0], acc[i][1], acc[i][2], acc[i][3]};
        *(float4*)&C[(size_t)(m0 + ty * 4 + i) * Nn + n0 + tx * 4] = o;
    }
}

// ---------------- attention scalars: as/ad [N,4] ----------------
__global__ __launch_bounds__(256) void k_alpha(const float* __restrict__ h,
    const float* __restrict__ att_s, const float* __restrict__ att_d,
    float* __restrict__ as_, float* __restrict__ ad_){
    int gt   = blockIdx.x * 256 + threadIdx.x;
    int wid  = gt >> 6;            // one wave per (node, head)
    int lane = threadIdx.x & 63;
    int n = wid >> 2, hh = wid & 3;
    const float* row = h + (size_t)n * HCdim + hh * 128;
    float2 hv = *(const float2*)(row + lane * 2);
    float2 sv = *(const float2*)(att_s + hh * 128 + lane * 2);
    float2 dv = *(const float2*)(att_d + hh * 128 + lane * 2);
    float ss = hv.x * sv.x + hv.y * sv.y;
    float sd = hv.x * dv.x + hv.y * dv.y;
    #pragma unroll
    for (int off = 32; off; off >>= 1){ ss += __shfl_down(ss, off); sd += __shfl_down(sd, off); }
    if (lane == 0){ as_[n * 4 + hh] = ss; ad_[n * 4 + hh] = sd; }
}

// ---------------- per-node softmax + message aggregation + bias + elu ----------------
__global__ __launch_bounds__(128) void k_aggregate(const float* __restrict__ h,
    const int* __restrict__ offs, const int* __restrict__ csr,
    const float* __restrict__ as_, const float* __restrict__ ad_,
    const float* __restrict__ bias, float* __restrict__ out){
    int n    = blockIdx.x;
    int tid  = threadIdx.x;
    int head = tid >> 5;               // thread covers channels [4*tid,4*tid+4) -> head = tid/32
    int start = offs[n], end = offs[n + 1];
    float adh = ad_[n * 4 + head];
    // pass 1: softmax denominator for this head (strided over 32-thread head group)
    float dsum = 0.f;
    for (int j = start + (tid & 31); j < end; j += 32){
        int s = csr[j];
        dsum += __expf(lrelu(as_[s * 4 + head] + adh));
    }
    #pragma unroll
    for (int off = 16; off; off >>= 1) dsum += __shfl_xor(dsum, off);  // stays within 32-lane half
    float rden = 1.f / (dsum + 1e-16f);
    // pass 2: weighted aggregation
    float4 acc = {0.f, 0.f, 0.f, 0.f};
    for (int j = start; j < end; j++){
        int s = csr[j];
        float w = __expf(lrelu(as_[s * 4 + head] + adh)) * rden;
        float4 hv = *(const float4*)(h + (size_t)s * HCdim + tid * 4);
        acc.x = fmaf(w, hv.x, acc.x);
        acc.y = fmaf(w, hv.y, acc.y);
        acc.z = fmaf(w, hv.z, acc.z);
        acc.w = fmaf(w, hv.w, acc.w);
    }
    float4 b4 = *(const float4*)(bias + tid * 4);
    float4 o;
    o.x = eluf(acc.x + b4.x);
    o.y = eluf(acc.y + b4.y);
    o.z = eluf(acc.z + b4.z);
    o.w = eluf(acc.w + b4.w);
    *(float4*)(out + (size_t)n * HCdim + tid * 4) = o;
}

// ---------------- pooling: x2[n] = h2[n,:] . p2w + p2b ----------------
__global__ __launch_bounds__(256) void k_pool(const float* __restrict__ h2,
    const float* __restrict__ pw, const float* __restrict__ pb, float* __restrict__ x2){
    int wave = threadIdx.x >> 6;
    int lane = threadIdx.x & 63;
    int n = blockIdx.x * 4 + wave;
    const float* row = h2 + (size_t)n * HCdim + lane * 8;
    const float* wr  = pw + lane * 8;
    float s = 0.f;
    #pragma unroll
    for (int i = 0; i < 8; i += 4){
        float4 hv = *(const float4*)(row + i);
        float4 wv = *(const float4*)(wr + i);
        s += hv.x * wv.x + hv.y * wv.y + hv.z * wv.z + hv.w * wv.w;
    }
    #pragma unroll
    for (int off = 32; off; off >>= 1) s += __shfl_down(s, off);
    if (lane == 0) x2[n] = s + pb[0];
}

// ---------------- layernorm + encoder MLP + outputs ----------------
__global__ __launch_bounds__(256) void k_encoder(const float* __restrict__ x2,
    const float* __restrict__ lng, const float* __restrict__ lnb,
    const float* __restrict__ fw1, const float* __restrict__ fb1,
    const float* __restrict__ fw2, const float* __restrict__ fb2,
    const float* __restrict__ fw3, const float* __restrict__ fb3,
    const float* __restrict__ fw4, const float* __restrict__ fb4,
    const float* __restrict__ lw,  const float* __restrict__ lb,
    float* __restrict__ out){
    __shared__ float xn[1024];
    __shared__ float e1[512];
    __shared__ float e2[256];
    __shared__ float e3[128];
    __shared__ float red[8];
    __shared__ float stats[2];
    int b = blockIdx.x, tid = threadIdx.x;
    float4 v = *(const float4*)(x2 + b * 1024 + tid * 4);
    float s  = v.x + v.y + v.z + v.w;
    float sq = v.x * v.x + v.y * v.y + v.z * v.z + v.w * v.w;
    #pragma unroll
    for (int off = 32; off; off >>= 1){ s += __shfl_down(s, off); sq += __shfl_down(sq, off); }
    if ((tid & 63) == 0){ red[(tid >> 6) * 2] = s; red[(tid >> 6) * 2 + 1] = sq; }
    __syncthreads();
    if (tid == 0){
        float S  = red[0] + red[2] + red[4] + red[6];
        float SQ = red[1] + red[3] + red[5] + red[7];
        float mu  = S * (1.f / 1024.f);
        float var = SQ * (1.f / 1024.f) - mu * mu;
        stats[0] = mu; stats[1] = rsqrtf(var + 1e-5f);
    }
    __syncthreads();
    float mu = stats[0], r = stats[1];
    float4 g4  = *(const float4*)(lng + tid * 4);
    float4 bb4 = *(const float4*)(lnb + tid * 4);
    float4 o;
    o.x = (v.x - mu) * r * g4.x + bb4.x;
    o.y = (v.y - mu) * r * g4.y + bb4.y;
    o.z = (v.z - mu) * r * g4.z + bb4.z;
    o.w = (v.w - mu) * r * g4.w + bb4.w;
    *(float4*)&xn[tid * 4] = o;
    *(float4*)(out + b * 1024 + tid * 4) = o;   // multiscale output
    __syncthreads();
    // L1: 1024 -> 512
    float a0 = fb1[tid], a1 = fb1[tid + 256];
    for (int i = 0; i < 1024; i++){
        float xv = xn[i];
        a0 = fmaf(xv, fw1[i * 512 + tid],       a0);
        a1 = fmaf(xv, fw1[i * 512 + tid + 256], a1);
    }
    e1[tid] = eluf(a0); e1[tid + 256] = eluf(a1);
    __syncthreads();
    // L2: 512 -> 256
    float a = fb2[tid];
    for (int i = 0; i < 512; i++) a = fmaf(e1[i], fw2[i * 256 + tid], a);
    e2[tid] = eluf(a);
    __syncthreads();
    // L3: 256 -> 128
    if (tid < 128){
        float a3 = fb3[tid];
        for (int i = 0; i < 256; i++) a3 = fmaf(e2[i], fw3[i * 128 + tid], a3);
        e3[tid] = eluf(a3);
    }
    __syncthreads();
    // L4: 128 -> 64, then pred
    if (tid < 64){
        float a4 = fb4[tid];
        for (int i = 0; i < 128; i++) a4 = fmaf(e3[i], fw4[i * 64 + tid], a4);
        float ev = eluf(a4);
        out[16384 + b * 64 + tid] = ev;         // e output
        float p = ev * lw[tid];
        #pragma unroll
        for (int off = 32; off; off >>= 1) p += __shfl_down(p, off);
        if (tid == 0) out[16384 + 1024 + b] = p + lb[0];  // pred output
    }
}

extern "C" void kernel_launch(void* const* d_in, const int* in_sizes, int n_in,
                              void* d_out, int out_size, void* d_ws, size_t ws_size,
                              hipStream_t stream) {
    const float* x        = (const float*)d_in[0];
    const int*   ei       = (const int*)  d_in[1];   // [2][E] flat
    const float* W1       = (const float*)d_in[3];
    const float* att_src1 = (const float*)d_in[4];
    const float* att_dst1 = (const float*)d_in[5];
    const float* b1       = (const float*)d_in[6];
    const float* W2       = (const float*)d_in[7];
    const float* att_src2 = (const float*)d_in[8];
    const float* att_dst2 = (const float*)d_in[9];
    const float* b2       = (const float*)d_in[10];
    const float* p2w      = (const float*)d_in[13];
    const float* p2b      = (const float*)d_in[14];
    const float* ln_g     = (const float*)d_in[15];
    const float* ln_b     = (const float*)d_in[16];
    const float* fw1      = (const float*)d_in[17];
    const float* fb1      = (const float*)d_in[18];
    const float* fw2      = (const float*)d_in[19];
    const float* fb2      = (const float*)d_in[20];
    const float* fw3      = (const float*)d_in[21];
    const float* fb3      = (const float*)d_in[22];
    const float* fw4      = (const float*)d_in[23];
    const float* fb4      = (const float*)d_in[24];
    const float* lw       = (const float*)d_in[25];
    const float* lb       = (const float*)d_in[26];
    float* out = (float*)d_out;

    // workspace layout (all offsets 256B-aligned), ~69 MB total
    char* w = (char*)d_ws;
    float* h_pre  = (float*)(w);                 // 16384*512 f32 = 32 MB
    float* h_out  = (float*)(w + 33554432);      // 32 MB
    float* asb    = (float*)(w + 67108864);      // N*4
    float* adb    = (float*)(w + 67371008);      // N*4
    int*   deg    = (int*)  (w + 67633152);      // N
    int*   cursor = (int*)  (w + 67698688);      // N (adjacent to deg)
    int*   offs   = (int*)  (w + 67764224);      // N+1
    int*   csr    = (int*)  (w + 67830016);      // EP_ ints
    float* x2b    = (float*)(w + 68944128);      // 16*1024

    // ---- CSR build (shared by both GAT layers) ----
    k_zero_i <<<(2 * NN + 255) / 256, 256, 0, stream>>>(deg, 2 * NN);  // deg + cursor
    k_degree <<<(EP_ + 255) / 256, 256, 0, stream>>>(ei, deg);
    k_scan   <<<1, 1024, 0, stream>>>(deg, offs);
    k_scatter<<<(EP_ + 255) / 256, 256, 0, stream>>>(ei, offs, cursor, csr);

    dim3 ggrid(HCdim / 64, NN / 64);
    // ---- GAT layer 1 ----
    gemm_fp32  <<<ggrid, 256, 0, stream>>>(x, W1, h_pre, NN, HCdim, DIN);
    k_alpha    <<<NN * NHEAD / 4, 256, 0, stream>>>(h_pre, att_src1, att_dst1, asb, adb);
    k_aggregate<<<NN, 128, 0, stream>>>(h_pre, offs, csr, asb, adb, b1, h_out);
    // ---- GAT layer 2 ----
    gemm_fp32  <<<ggrid, 256, 0, stream>>>(h_out, W2, h_pre, NN, HCdim, HCdim);
    k_alpha    <<<NN * NHEAD / 4, 256, 0, stream>>>(h_pre, att_src2, att_dst2, asb, adb);
    k_aggregate<<<NN, 128, 0, stream>>>(h_pre, offs, csr, asb, adb, b2, h_out);
    // ---- pooling + layernorm + encoder MLP ----
    k_pool   <<<NN / 4, 256, 0, stream>>>(h_out, p2w, p2b, x2b);
    k_encoder<<<16, 256, 0, stream>>>(x2b, ln_g, ln_b, fw1, fb1, fw2, fb2,
                                      fw3, fb3, fw4, fb4, lw, lb, out);
}

// Round 2
// 462.493 us; speedup vs baseline: 1.7317x; 1.7317x over previous
//
#include <hip/hip_runtime.h>
#include <math.h>

#define NN    16384     // nodes
#define DIN   1024
#define HCdim 512       // H*C
#define NHEAD 4
#define NE_   262144    // edges (without self loops)
#define EP_   (NE_ + NN) // with self loops

using short8  = __attribute__((ext_vector_type(8))) short;
using floatx4 = __attribute__((ext_vector_type(4))) float;

__device__ __forceinline__ float eluf(float x){ return x > 0.f ? x : expm1f(x); }
__device__ __forceinline__ float lrelu(float x){ return x > 0.f ? x : 0.2f * x; }
__device__ __forceinline__ float bf2f(unsigned short u){
    union { unsigned int i; float f; } c; c.i = ((unsigned int)u) << 16; return c.f;
}
__device__ __forceinline__ unsigned short f2b(float f){
    union { float f; unsigned int u; } c; c.f = f;
    unsigned int u = c.u;
    return (unsigned short)((u + 0x7FFFu + ((u >> 16) & 1u)) >> 16);   // RNE
}

// ---------------- CSR build ----------------
__global__ void k_zero_i(int* __restrict__ p, int n){
    int i = blockIdx.x * 256 + threadIdx.x;
    if (i < n) p[i] = 0;
}

__global__ void k_degree(const int* __restrict__ ei, int* __restrict__ deg){
    int i = blockIdx.x * 256 + threadIdx.x;
    if (i >= EP_) return;
    int d = (i < NE_) ? ei[NE_ + i] : (i - NE_);
    atomicAdd(&deg[d], 1);
}

__global__ __launch_bounds__(1024) void k_scan(const int* __restrict__ deg, int* __restrict__ offs){
    __shared__ int s[1024];
    int tid  = threadIdx.x;
    int base = tid * 16;
    int local[16];
    int sum = 0;
    #pragma unroll
    for (int i = 0; i < 16; i++){ local[i] = deg[base + i]; sum += local[i]; }
    s[tid] = sum;
    __syncthreads();
    for (int off = 1; off < 1024; off <<= 1){
        int v = (tid >= off) ? s[tid - off] : 0;
        __syncthreads();
        s[tid] += v;
        __syncthreads();
    }
    int run = (tid == 0) ? 0 : s[tid - 1];
    #pragma unroll
    for (int i = 0; i < 16; i++){ offs[base + i] = run; run += local[i]; }
    if (tid == 1023) offs[NN] = run;
}

__global__ void k_scatter(const int* __restrict__ ei, const int* __restrict__ offs,
                          int* __restrict__ cursor, int* __restrict__ csr){
    int i = blockIdx.x * 256 + threadIdx.x;
    if (i >= EP_) return;
    int srcv, dstv;
    if (i < NE_){ srcv = ei[i]; dstv = ei[NE_ + i]; }
    else        { srcv = dstv = i - NE_; }
    int pos = offs[dstv] + atomicAdd(&cursor[dstv], 1);
    csr[pos] = srcv;
}

// ---------------- casts ----------------
__global__ __launch_bounds__(256) void k_cast_x(const float* __restrict__ x, ushort* __restrict__ xb){
    int i = blockIdx.x * 256 + threadIdx.x;
    float4 v = *(const float4*)(x + (size_t)i * 4);
    ushort4 o = { f2b(v.x), f2b(v.y), f2b(v.z), f2b(v.w) };
    *(ushort4*)(xb + (size_t)i * 4) = o;
}

// W[K][Nn] fp32 -> WT[Nn][K] bf16 ;  kshift = log2(K/4)
__global__ __launch_bounds__(256) void k_castT(const float* __restrict__ W, ushort* __restrict__ WT,
                                               int K, int Nn, int kshift){
    int t  = blockIdx.x * 256 + threadIdx.x;
    int n  = t >> kshift;
    int kb = (t & ((1 << kshift) - 1)) * 4;
    ushort4 o;
    o.x = f2b(W[(size_t)(kb + 0) * Nn + n]);
    o.y = f2b(W[(size_t)(kb + 1) * Nn + n]);
    o.z = f2b(W[(size_t)(kb + 2) * Nn + n]);
    o.w = f2b(W[(size_t)(kb + 3) * Nn + n]);
    *(ushort4*)(WT + (size_t)n * K + kb) = o;
}

// ---------------- bf16 MFMA GEMM: C[M,Nn] = A[M,K] @ BT[Nn,K]^T ----------------
// 128x128 block tile, BK=32, 4 waves each computing 64x64 via 4x4 16x16x32 MFMAs.
__global__ __launch_bounds__(256) void gemm_bf16(const ushort* __restrict__ A,
                                                 const ushort* __restrict__ BT,
                                                 ushort* __restrict__ C,
                                                 int M, int Nn, int K){
    __shared__ ushort As[128 * 32];
    __shared__ ushort Bs[128 * 32];
    int tid = threadIdx.x;
    int m0 = blockIdx.y * 128, n0 = blockIdx.x * 128;
    int lane = tid & 63, w = tid >> 6;
    int wm = (w >> 1) * 64, wn = (w & 1) * 64;
    int la = lane & 15, qd = lane >> 4;

    // staging: thread t covers row=(t>>2)+{0,64}, k-chunk=(t&3)*8 (16B each)
    int srow = tid >> 2, schunk = (tid & 3) * 8;
    const ushort* Ag = A  + (size_t)(m0 + srow) * K + schunk;
    const ushort* Bg = BT + (size_t)(n0 + srow) * K + schunk;
    ushort* Asw = &As[srow * 32 + schunk];
    ushort* Bsw = &Bs[srow * 32 + schunk];

    floatx4 acc[4][4] = {};
    for (int k0 = 0; k0 < K; k0 += 32){
        uint4 a0 = *(const uint4*)(Ag + k0);
        uint4 a1 = *(const uint4*)(Ag + (size_t)64 * K + k0);
        uint4 b0 = *(const uint4*)(Bg + k0);
        uint4 b1 = *(const uint4*)(Bg + (size_t)64 * K + k0);
        __syncthreads();
        *(uint4*)Asw            = a0;
        *(uint4*)(Asw + 64*32)  = a1;
        *(uint4*)Bsw            = b0;
        *(uint4*)(Bsw + 64*32)  = b1;
        __syncthreads();
        short8 af[4], bf[4];
        #pragma unroll
        for (int i = 0; i < 4; i++){
            af[i] = *(const short8*)&As[(wm + i*16 + la) * 32 + qd * 8];
            bf[i] = *(const short8*)&Bs[(wn + i*16 + la) * 32 + qd * 8];
        }
        #pragma unroll
        for (int i = 0; i < 4; i++)
            #pragma unroll
            for (int j = 0; j < 4; j++)
                acc[i][j] = __builtin_amdgcn_mfma_f32_16x16x32_bf16(af[i], bf[j], acc[i][j], 0, 0, 0);
    }
    // C/D layout: col = lane&15, row = qd*4 + r  (m89/m91-verified)
    #pragma unroll
    for (int i = 0; i < 4; i++)
        #pragma unroll
        for (int j = 0; j < 4; j++){
            int col = n0 + wn + j * 16 + la;
            #pragma unroll
            for (int r = 0; r < 4; r++){
                int row = m0 + wm + i * 16 + qd * 4 + r;
                C[(size_t)row * Nn + col] = f2b(acc[i][j][r]);
            }
        }
}

// ---------------- attention scalars: as/ad [N,4] from bf16 h ----------------
__global__ __launch_bounds__(256) void k_alpha(const ushort* __restrict__ h,
    const float* __restrict__ att_s, const float* __restrict__ att_d,
    float* __restrict__ as_, float* __restrict__ ad_){
    int gt   = blockIdx.x * 256 + threadIdx.x;
    int wid  = gt >> 6;            // one wave per (node, head)
    int lane = threadIdx.x & 63;
    int n = wid >> 2, hh = wid & 3;
    unsigned int hv = *(const unsigned int*)(h + (size_t)n * HCdim + hh * 128 + lane * 2);
    float h0 = bf2f(hv & 0xffff), h1 = bf2f(hv >> 16);
    float2 sv = *(const float2*)(att_s + hh * 128 + lane * 2);
    float2 dv = *(const float2*)(att_d + hh * 128 + lane * 2);
    float ss = h0 * sv.x + h1 * sv.y;
    float sd = h0 * dv.x + h1 * dv.y;
    #pragma unroll
    for (int off = 32; off; off >>= 1){ ss += __shfl_down(ss, off); sd += __shfl_down(sd, off); }
    if (lane == 0){ as_[n * 4 + hh] = ss; ad_[n * 4 + hh] = sd; }
}

// ---------------- per-node softmax + aggregation + bias + elu (bf16 in/out) ----------------
__global__ __launch_bounds__(128) void k_aggregate(const ushort* __restrict__ h,
    const int* __restrict__ offs, const int* __restrict__ csr,
    const float* __restrict__ as_, const float* __restrict__ ad_,
    const float* __restrict__ bias, ushort* __restrict__ out){
    int n    = blockIdx.x;
    int tid  = threadIdx.x;
    int head = tid >> 5;               // thread covers channels [4*tid,4*tid+4)
    int start = offs[n], end = offs[n + 1];
    float adh = ad_[n * 4 + head];
    float dsum = 0.f;
    for (int j = start + (tid & 31); j < end; j += 32){
        int s = csr[j];
        dsum += __expf(lrelu(as_[s * 4 + head] + adh));
    }
    #pragma unroll
    for (int off = 16; off; off >>= 1) dsum += __shfl_xor(dsum, off);  // within 32-lane head group
    float rden = 1.f / (dsum + 1e-16f);
    float a0 = 0.f, a1 = 0.f, a2 = 0.f, a3 = 0.f;
    for (int j = start; j < end; j++){
        int s = csr[j];
        float wgt = __expf(lrelu(as_[s * 4 + head] + adh)) * rden;
        uint2 hv = *(const uint2*)(h + (size_t)s * HCdim + tid * 4);
        a0 = fmaf(wgt, bf2f(hv.x & 0xffff), a0);
        a1 = fmaf(wgt, bf2f(hv.x >> 16),    a1);
        a2 = fmaf(wgt, bf2f(hv.y & 0xffff), a2);
        a3 = fmaf(wgt, bf2f(hv.y >> 16),    a3);
    }
    float4 b4 = *(const float4*)(bias + tid * 4);
    ushort4 o;
    o.x = f2b(eluf(a0 + b4.x));
    o.y = f2b(eluf(a1 + b4.y));
    o.z = f2b(eluf(a2 + b4.z));
    o.w = f2b(eluf(a3 + b4.w));
    *(ushort4*)(out + (size_t)n * HCdim + tid * 4) = o;
}

// ---------------- pooling: x2[n] = h2[n,:] . p2w + p2b  (bf16 h2) ----------------
__global__ __launch_bounds__(256) void k_pool(const ushort* __restrict__ h2,
    const float* __restrict__ pw, const float* __restrict__ pb, float* __restrict__ x2){
    int wave = threadIdx.x >> 6;
    int lane = threadIdx.x & 63;
    int n = blockIdx.x * 4 + wave;
    uint4 hv = *(const uint4*)(h2 + (size_t)n * HCdim + lane * 8);
    const float* wr = pw + lane * 8;
    float4 w0 = *(const float4*)(wr);
    float4 w1 = *(const float4*)(wr + 4);
    float s = bf2f(hv.x & 0xffff) * w0.x + bf2f(hv.x >> 16) * w0.y
            + bf2f(hv.y & 0xffff) * w0.z + bf2f(hv.y >> 16) * w0.w
            + bf2f(hv.z & 0xffff) * w1.x + bf2f(hv.z >> 16) * w1.y
            + bf2f(hv.w & 0xffff) * w1.z + bf2f(hv.w >> 16) * w1.w;
    #pragma unroll
    for (int off = 32; off; off >>= 1) s += __shfl_down(s, off);
    if (lane == 0) x2[n] = s + pb[0];
}

// ---------------- layernorm + encoder MLP + outputs ----------------
__global__ __launch_bounds__(256) void k_encoder(const float* __restrict__ x2,
    const float* __restrict__ lng, const float* __restrict__ lnb,
    const float* __restrict__ fw1, const float* __restrict__ fb1,
    const float* __restrict__ fw2, const float* __restrict__ fb2,
    const float* __restrict__ fw3, const float* __restrict__ fb3,
    const float* __restrict__ fw4, const float* __restrict__ fb4,
    const float* __restrict__ lw,  const float* __restrict__ lb,
    float* __restrict__ out){
    __shared__ float xn[1024];
    __shared__ float e1[512];
    __shared__ float e2[256];
    __shared__ float e3[128];
    __shared__ float red[8];
    __shared__ float stats[2];
    int b = blockIdx.x, tid = threadIdx.x;
    float4 v = *(const float4*)(x2 + b * 1024 + tid * 4);
    float s  = v.x + v.y + v.z + v.w;
    float sq = v.x * v.x + v.y * v.y + v.z * v.z + v.w * v.w;
    #pragma unroll
    for (int off = 32; off; off >>= 1){ s += __shfl_down(s, off); sq += __shfl_down(sq, off); }
    if ((tid & 63) == 0){ red[(tid >> 6) * 2] = s; red[(tid >> 6) * 2 + 1] = sq; }
    __syncthreads();
    if (tid == 0){
        float S  = red[0] + red[2] + red[4] + red[6];
        float SQ = red[1] + red[3] + red[5] + red[7];
        float mu  = S * (1.f / 1024.f);
        float var = SQ * (1.f / 1024.f) - mu * mu;
        stats[0] = mu; stats[1] = rsqrtf(var + 1e-5f);
    }
    __syncthreads();
    float mu = stats[0], r = stats[1];
    float4 g4  = *(const float4*)(lng + tid * 4);
    float4 bb4 = *(const float4*)(lnb + tid * 4);
    float4 o;
    o.x = (v.x - mu) * r * g4.x + bb4.x;
    o.y = (v.y - mu) * r * g4.y + bb4.y;
    o.z = (v.z - mu) * r * g4.z + bb4.z;
    o.w = (v.w - mu) * r * g4.w + bb4.w;
    *(float4*)&xn[tid * 4] = o;
    *(float4*)(out + b * 1024 + tid * 4) = o;   // multiscale output
    __syncthreads();
    float a0 = fb1[tid], a1 = fb1[tid + 256];
    for (int i = 0; i < 1024; i++){
        float xv = xn[i];
        a0 = fmaf(xv, fw1[i * 512 + tid],       a0);
        a1 = fmaf(xv, fw1[i * 512 + tid + 256], a1);
    }
    e1[tid] = eluf(a0); e1[tid + 256] = eluf(a1);
    __syncthreads();
    float a = fb2[tid];
    for (int i = 0; i < 512; i++) a = fmaf(e1[i], fw2[i * 256 + tid], a);
    e2[tid] = eluf(a);
    __syncthreads();
    if (tid < 128){
        float a3 = fb3[tid];
        for (int i = 0; i < 256; i++) a3 = fmaf(e2[i], fw3[i * 128 + tid], a3);
        e3[tid] = eluf(a3);
    }
    __syncthreads();
    if (tid < 64){
        float a4 = fb4[tid];
        for (int i = 0; i < 128; i++) a4 = fmaf(e3[i], fw4[i * 64 + tid], a4);
        float ev = eluf(a4);
        out[16384 + b * 64 + tid] = ev;         // e output
        float p = ev * lw[tid];
        #pragma unroll
        for (int off = 32; off; off >>= 1) p += __shfl_down(p, off);
        if (tid == 0) out[16384 + 1024 + b] = p + lb[0];  // pred output
    }
}

extern "C" void kernel_launch(void* const* d_in, const int* in_sizes, int n_in,
                              void* d_out, int out_size, void* d_ws, size_t ws_size,
                              hipStream_t stream) {
    const float* x        = (const float*)d_in[0];
    const int*   ei       = (const int*)  d_in[1];
    const float* W1       = (const float*)d_in[3];
    const float* att_src1 = (const float*)d_in[4];
    const float* att_dst1 = (const float*)d_in[5];
    const float* b1       = (const float*)d_in[6];
    const float* W2       = (const float*)d_in[7];
    const float* att_src2 = (const float*)d_in[8];
    const float* att_dst2 = (const float*)d_in[9];
    const float* b2       = (const float*)d_in[10];
    const float* p2w      = (const float*)d_in[13];
    const float* p2b      = (const float*)d_in[14];
    const float* ln_g     = (const float*)d_in[15];
    const float* ln_b     = (const float*)d_in[16];
    const float* fw1      = (const float*)d_in[17];
    const float* fb1      = (const float*)d_in[18];
    const float* fw2      = (const float*)d_in[19];
    const float* fb2      = (const float*)d_in[20];
    const float* fw3      = (const float*)d_in[21];
    const float* fb3      = (const float*)d_in[22];
    const float* fw4      = (const float*)d_in[23];
    const float* fb4      = (const float*)d_in[24];
    const float* lw       = (const float*)d_in[25];
    const float* lb       = (const float*)d_in[26];
    float* out = (float*)d_out;

    // workspace layout (bytes), ~53.8 MB total
    char* w = (char*)d_ws;
    ushort* xb   = (ushort*)(w);                 // 32 MB: xb; later h1b (@0) + h2b (@16M)
    ushort* h1b  = (ushort*)(w);                 // 16 MB (reuses xb after GEMM1)
    ushort* h2b  = (ushort*)(w + 16777216);      // 16 MB
    ushort* hpre = (ushort*)(w + 33554432);      // 16 MB bf16 GEMM out
    ushort* W1T  = (ushort*)(w + 50331648);      // 1 MB
    ushort* W2T  = (ushort*)(w + 51380224);      // 0.5 MB
    float* asb   = (float*)(w + 51904512);       // 256 KB
    float* adb   = (float*)(w + 52166656);       // 256 KB
    int*   deg   = (int*)  (w + 52428800);       // 64 KB
    int*   cursor= (int*)  (w + 52494336);       // 64 KB
    int*   offs  = (int*)  (w + 52559872);       // 64 KB + 4
    int*   csr   = (int*)  (w + 52625664);       // EP_ ints
    float* x2b   = (float*)(w + 53739776);       // 64 KB

    // ---- CSR build ----
    k_zero_i <<<(2 * NN + 255) / 256, 256, 0, stream>>>(deg, 2 * NN);
    k_degree <<<(EP_ + 255) / 256, 256, 0, stream>>>(ei, deg);
    k_scan   <<<1, 1024, 0, stream>>>(deg, offs);
    k_scatter<<<(EP_ + 255) / 256, 256, 0, stream>>>(ei, offs, cursor, csr);

    // ---- casts ----
    k_cast_x<<<NN * DIN / 4 / 256, 256, 0, stream>>>(x, xb);
    k_castT <<<DIN * HCdim / 4 / 256, 256, 0, stream>>>(W1, W1T, DIN, HCdim, 8);
    k_castT <<<HCdim * HCdim / 4 / 256, 256, 0, stream>>>(W2, W2T, HCdim, HCdim, 7);

    dim3 ggrid(HCdim / 128, NN / 128);
    // ---- GAT layer 1 ----
    gemm_bf16  <<<ggrid, 256, 0, stream>>>(xb, W1T, hpre, NN, HCdim, DIN);
    k_alpha    <<<NN * NHEAD / 4, 256, 0, stream>>>(hpre, att_src1, att_dst1, asb, adb);
    k_aggregate<<<NN, 128, 0, stream>>>(hpre, offs, csr, asb, adb, b1, h1b);
    // ---- GAT layer 2 ----
    gemm_bf16  <<<ggrid, 256, 0, stream>>>(h1b, W2T, hpre, NN, HCdim, HCdim);
    k_alpha    <<<NN * NHEAD / 4, 256, 0, stream>>>(hpre, att_src2, att_dst2, asb, adb);
    k_aggregate<<<NN, 128, 0, stream>>>(hpre, offs, csr, asb, adb, b2, h2b);
    // ---- pooling + layernorm + encoder MLP ----
    k_pool   <<<NN / 4, 256, 0, stream>>>(h2b, p2w, p2b, x2b);
    k_encoder<<<16, 256, 0, stream>>>(x2b, ln_g, ln_b, fw1, fb1, fw2, fb2,
                                      fw3, fb3, fw4, fb4, lw, lb, out);
}

// Round 3
// 396.904 us; speedup vs baseline: 2.0179x; 1.1652x over previous
//
#include <hip/hip_runtime.h>
#include <math.h>

#define NN    16384     // nodes
#define DIN   1024
#define HCdim 512       // H*C
#define NHEAD 4
#define NE_   262144    // edges (without self loops)
#define EP_   (NE_ + NN) // with self loops

using short8  = __attribute__((ext_vector_type(8))) short;
using floatx4 = __attribute__((ext_vector_type(4))) float;

__device__ __forceinline__ float eluf(float x){ return x > 0.f ? x : expm1f(x); }
__device__ __forceinline__ float lrelu(float x){ return x > 0.f ? x : 0.2f * x; }
__device__ __forceinline__ float bf2f(unsigned short u){
    union { unsigned int i; float f; } c; c.i = ((unsigned int)u) << 16; return c.f;
}
__device__ __forceinline__ unsigned short f2b(float f){
    union { float f; unsigned int u; } c; c.f = f;
    unsigned int u = c.u;
    return (unsigned short)((u + 0x7FFFu + ((u >> 16) & 1u)) >> 16);   // RNE
}

// ---------------- CSR build ----------------
__global__ void k_zero_i(int* __restrict__ p, int n){
    int i = blockIdx.x * 256 + threadIdx.x;
    if (i < n) p[i] = 0;
}

__global__ void k_degree(const int* __restrict__ ei, int* __restrict__ deg){
    int i = blockIdx.x * 256 + threadIdx.x;
    if (i >= EP_) return;
    int d = (i < NE_) ? ei[NE_ + i] : (i - NE_);
    atomicAdd(&deg[d], 1);
}

__global__ __launch_bounds__(1024) void k_scan(const int* __restrict__ deg, int* __restrict__ offs){
    __shared__ int s[1024];
    int tid  = threadIdx.x;
    int base = tid * 16;
    int local[16];
    int sum = 0;
    #pragma unroll
    for (int i = 0; i < 16; i++){ local[i] = deg[base + i]; sum += local[i]; }
    s[tid] = sum;
    __syncthreads();
    for (int off = 1; off < 1024; off <<= 1){
        int v = (tid >= off) ? s[tid - off] : 0;
        __syncthreads();
        s[tid] += v;
        __syncthreads();
    }
    int run = (tid == 0) ? 0 : s[tid - 1];
    #pragma unroll
    for (int i = 0; i < 16; i++){ offs[base + i] = run; run += local[i]; }
    if (tid == 1023) offs[NN] = run;
}

__global__ void k_scatter(const int* __restrict__ ei, const int* __restrict__ offs,
                          int* __restrict__ cursor, int* __restrict__ csr){
    int i = blockIdx.x * 256 + threadIdx.x;
    if (i >= EP_) return;
    int srcv, dstv;
    if (i < NE_){ srcv = ei[i]; dstv = ei[NE_ + i]; }
    else        { srcv = dstv = i - NE_; }
    int pos = offs[dstv] + atomicAdd(&cursor[dstv], 1);
    csr[pos] = srcv;
}

// ---------------- casts ----------------
__global__ __launch_bounds__(256) void k_cast_x(const float* __restrict__ x, ushort* __restrict__ xb){
    int i = blockIdx.x * 256 + threadIdx.x;
    float4 v = *(const float4*)(x + (size_t)i * 4);
    ushort4 o = { f2b(v.x), f2b(v.y), f2b(v.z), f2b(v.w) };
    *(ushort4*)(xb + (size_t)i * 4) = o;
}

// W[K][Nn] fp32 -> WT[Nn][K] bf16 ;  kshift = log2(K/4)
__global__ __launch_bounds__(256) void k_castT(const float* __restrict__ W, ushort* __restrict__ WT,
                                               int K, int Nn, int kshift){
    int t  = blockIdx.x * 256 + threadIdx.x;
    int n  = t >> kshift;
    int kb = (t & ((1 << kshift) - 1)) * 4;
    ushort4 o;
    o.x = f2b(W[(size_t)(kb + 0) * Nn + n]);
    o.y = f2b(W[(size_t)(kb + 1) * Nn + n]);
    o.z = f2b(W[(size_t)(kb + 2) * Nn + n]);
    o.w = f2b(W[(size_t)(kb + 3) * Nn + n]);
    *(ushort4*)(WT + (size_t)n * K + kb) = o;
}

// ---------------- bf16 MFMA GEMM: C[M,Nn] = A[M,K] @ BT[Nn,K]^T ----------------
__global__ __launch_bounds__(256) void gemm_bf16(const ushort* __restrict__ A,
                                                 const ushort* __restrict__ BT,
                                                 ushort* __restrict__ C,
                                                 int M, int Nn, int K){
    __shared__ ushort As[128 * 32];
    __shared__ ushort Bs[128 * 32];
    int tid = threadIdx.x;
    int m0 = blockIdx.y * 128, n0 = blockIdx.x * 128;
    int lane = tid & 63, w = tid >> 6;
    int wm = (w >> 1) * 64, wn = (w & 1) * 64;
    int la = lane & 15, qd = lane >> 4;

    int srow = tid >> 2, schunk = (tid & 3) * 8;
    const ushort* Ag = A  + (size_t)(m0 + srow) * K + schunk;
    const ushort* Bg = BT + (size_t)(n0 + srow) * K + schunk;
    ushort* Asw = &As[srow * 32 + schunk];
    ushort* Bsw = &Bs[srow * 32 + schunk];

    floatx4 acc[4][4] = {};
    for (int k0 = 0; k0 < K; k0 += 32){
        uint4 a0 = *(const uint4*)(Ag + k0);
        uint4 a1 = *(const uint4*)(Ag + (size_t)64 * K + k0);
        uint4 b0 = *(const uint4*)(Bg + k0);
        uint4 b1 = *(const uint4*)(Bg + (size_t)64 * K + k0);
        __syncthreads();
        *(uint4*)Asw            = a0;
        *(uint4*)(Asw + 64*32)  = a1;
        *(uint4*)Bsw            = b0;
        *(uint4*)(Bsw + 64*32)  = b1;
        __syncthreads();
        short8 af[4], bf[4];
        #pragma unroll
        for (int i = 0; i < 4; i++){
            af[i] = *(const short8*)&As[(wm + i*16 + la) * 32 + qd * 8];
            bf[i] = *(const short8*)&Bs[(wn + i*16 + la) * 32 + qd * 8];
        }
        #pragma unroll
        for (int i = 0; i < 4; i++)
            #pragma unroll
            for (int j = 0; j < 4; j++)
                acc[i][j] = __builtin_amdgcn_mfma_f32_16x16x32_bf16(af[i], bf[j], acc[i][j], 0, 0, 0);
    }
    #pragma unroll
    for (int i = 0; i < 4; i++)
        #pragma unroll
        for (int j = 0; j < 4; j++){
            int col = n0 + wn + j * 16 + la;
            #pragma unroll
            for (int r = 0; r < 4; r++){
                int row = m0 + wm + i * 16 + qd * 4 + r;
                C[(size_t)row * Nn + col] = f2b(acc[i][j][r]);
            }
        }
}

// ---------------- attention scalars: as/ad [N,4] from bf16 h ----------------
__global__ __launch_bounds__(256) void k_alpha(const ushort* __restrict__ h,
    const float* __restrict__ att_s, const float* __restrict__ att_d,
    float* __restrict__ as_, float* __restrict__ ad_){
    int gt   = blockIdx.x * 256 + threadIdx.x;
    int wid  = gt >> 6;
    int lane = threadIdx.x & 63;
    int n = wid >> 2, hh = wid & 3;
    unsigned int hv = *(const unsigned int*)(h + (size_t)n * HCdim + hh * 128 + lane * 2);
    float h0 = bf2f(hv & 0xffff), h1 = bf2f(hv >> 16);
    float2 sv = *(const float2*)(att_s + hh * 128 + lane * 2);
    float2 dv = *(const float2*)(att_d + hh * 128 + lane * 2);
    float ss = h0 * sv.x + h1 * sv.y;
    float sd = h0 * dv.x + h1 * dv.y;
    #pragma unroll
    for (int off = 32; off; off >>= 1){ ss += __shfl_down(ss, off); sd += __shfl_down(sd, off); }
    if (lane == 0){ as_[n * 4 + hh] = ss; ad_[n * 4 + hh] = sd; }
}

// ---------------- per-node softmax + aggregation + bias + elu (+ optional fused pool) ----------------
template<bool POOL>
__global__ __launch_bounds__(128) void k_aggregate(const ushort* __restrict__ h,
    const int* __restrict__ offs, const int* __restrict__ csr,
    const float* __restrict__ as_, const float* __restrict__ ad_,
    const float* __restrict__ bias, ushort* __restrict__ out,
    const float* __restrict__ pw, const float* __restrict__ pb, float* __restrict__ x2){
    __shared__ float rpool[2];
    int n    = blockIdx.x;
    int tid  = threadIdx.x;
    int head = tid >> 5;
    int start = offs[n], end = offs[n + 1];
    float adh = ad_[n * 4 + head];
    float dsum = 0.f;
    for (int j = start + (tid & 31); j < end; j += 32){
        int s = csr[j];
        dsum += __expf(lrelu(as_[s * 4 + head] + adh));
    }
    #pragma unroll
    for (int off = 16; off; off >>= 1) dsum += __shfl_xor(dsum, off);
    float rden = 1.f / (dsum + 1e-16f);
    float a0 = 0.f, a1 = 0.f, a2 = 0.f, a3 = 0.f;
    for (int j = start; j < end; j++){
        int s = csr[j];
        float wgt = __expf(lrelu(as_[s * 4 + head] + adh)) * rden;
        uint2 hv = *(const uint2*)(h + (size_t)s * HCdim + tid * 4);
        a0 = fmaf(wgt, bf2f(hv.x & 0xffff), a0);
        a1 = fmaf(wgt, bf2f(hv.x >> 16),    a1);
        a2 = fmaf(wgt, bf2f(hv.y & 0xffff), a2);
        a3 = fmaf(wgt, bf2f(hv.y >> 16),    a3);
    }
    float4 b4 = *(const float4*)(bias + tid * 4);
    float e0 = eluf(a0 + b4.x), e1 = eluf(a1 + b4.y);
    float e2 = eluf(a2 + b4.z), e3 = eluf(a3 + b4.w);
    ushort4 o = { f2b(e0), f2b(e1), f2b(e2), f2b(e3) };
    *(ushort4*)(out + (size_t)n * HCdim + tid * 4) = o;
    if (POOL){
        float4 w4 = *(const float4*)(pw + tid * 4);
        float s = e0 * w4.x + e1 * w4.y + e2 * w4.z + e3 * w4.w;
        #pragma unroll
        for (int off = 32; off; off >>= 1) s += __shfl_down(s, off);
        if ((tid & 63) == 0) rpool[tid >> 6] = s;
        __syncthreads();
        if (tid == 0) x2[n] = rpool[0] + rpool[1] + pb[0];
    }
}

// ---------------- layernorm: x2 [16,1024] -> xn (ws) + multiscale out ----------------
__global__ __launch_bounds__(256) void k_ln(const float* __restrict__ x2,
    const float* __restrict__ lng, const float* __restrict__ lnb,
    float* __restrict__ xnb, float* __restrict__ out){
    __shared__ float red[8];
    __shared__ float stats[2];
    int b = blockIdx.x, tid = threadIdx.x;
    float4 v = *(const float4*)(x2 + b * 1024 + tid * 4);
    float s  = v.x + v.y + v.z + v.w;
    float sq = v.x * v.x + v.y * v.y + v.z * v.z + v.w * v.w;
    #pragma unroll
    for (int off = 32; off; off >>= 1){ s += __shfl_down(s, off); sq += __shfl_down(sq, off); }
    if ((tid & 63) == 0){ red[(tid >> 6) * 2] = s; red[(tid >> 6) * 2 + 1] = sq; }
    __syncthreads();
    if (tid == 0){
        float S  = red[0] + red[2] + red[4] + red[6];
        float SQ = red[1] + red[3] + red[5] + red[7];
        float mu  = S * (1.f / 1024.f);
        float var = SQ * (1.f / 1024.f) - mu * mu;
        stats[0] = mu; stats[1] = rsqrtf(var + 1e-5f);
    }
    __syncthreads();
    float mu = stats[0], r = stats[1];
    float4 g4  = *(const float4*)(lng + tid * 4);
    float4 bb4 = *(const float4*)(lnb + tid * 4);
    float4 o;
    o.x = (v.x - mu) * r * g4.x + bb4.x;
    o.y = (v.y - mu) * r * g4.y + bb4.y;
    o.z = (v.z - mu) * r * g4.z + bb4.z;
    o.w = (v.w - mu) * r * g4.w + bb4.w;
    *(float4*)(xnb + b * 1024 + tid * 4) = o;
    *(float4*)(out + b * 1024 + tid * 4) = o;
}

// ---------------- FC layer: out[b, c] = elu(in[b,:] . W[:,c] + bias[c]) ----------------
// grid (NOUT/64, 16), block 256: tx = col within 64-block, ty = K-slice (4-way)
template<int K, int NOUT>
__global__ __launch_bounds__(256) void k_fc(const float* __restrict__ in,
    const float* __restrict__ W, const float* __restrict__ bias, float* __restrict__ outb){
    __shared__ float xs[K];
    __shared__ float red[4][64];
    int tid = threadIdx.x;
    int b = blockIdx.y, c0 = blockIdx.x * 64;
    int tx = tid & 63, ty = tid >> 6;
    for (int i = tid * 4; i < K; i += 1024)
        *(float4*)&xs[i] = *(const float4*)(in + b * K + i);
    __syncthreads();
    const float* wp = W + (size_t)(ty * (K / 4)) * NOUT + c0 + tx;
    float a = 0.f;
    #pragma unroll 8
    for (int i = 0; i < K / 4; i++)
        a = fmaf(xs[ty * (K / 4) + i], wp[(size_t)i * NOUT], a);
    red[ty][tx] = a;
    __syncthreads();
    if (ty == 0){
        float v = red[0][tx] + red[1][tx] + red[2][tx] + red[3][tx] + bias[c0 + tx];
        outb[b * NOUT + tx + c0] = eluf(v);
    }
}

// ---------------- final FC (128->64) + e output + pred ----------------
__global__ __launch_bounds__(256) void k_fc_final(const float* __restrict__ in,
    const float* __restrict__ W, const float* __restrict__ bias,
    const float* __restrict__ lw, const float* __restrict__ lb, float* __restrict__ out){
    __shared__ float xs[128];
    __shared__ float red[4][64];
    __shared__ float evs[64];
    int tid = threadIdx.x;
    int b = blockIdx.x;
    int tx = tid & 63, ty = tid >> 6;
    if (tid * 4 < 128)
        *(float4*)&xs[tid * 4] = *(const float4*)(in + b * 128 + tid * 4);
    __syncthreads();
    const float* wp = W + (size_t)(ty * 32) * 64 + tx;
    float a = 0.f;
    #pragma unroll
    for (int i = 0; i < 32; i++)
        a = fmaf(xs[ty * 32 + i], wp[(size_t)i * 64], a);
    red[ty][tx] = a;
    __syncthreads();
    if (ty == 0){
        float ev = eluf(red[0][tx] + red[1][tx] + red[2][tx] + red[3][tx] + bias[tx]);
        evs[tx] = ev;
        out[16384 + b * 64 + tx] = ev;
    }
    __syncthreads();
    if (ty == 0){
        float p = evs[tx] * lw[tx];
        #pragma unroll
        for (int off = 32; off; off >>= 1) p += __shfl_down(p, off);
        if (tx == 0) out[16384 + 1024 + b] = p + lb[0];
    }
}

extern "C" void kernel_launch(void* const* d_in, const int* in_sizes, int n_in,
                              void* d_out, int out_size, void* d_ws, size_t ws_size,
                              hipStream_t stream) {
    const float* x        = (const float*)d_in[0];
    const int*   ei       = (const int*)  d_in[1];
    const float* W1       = (const float*)d_in[3];
    const float* att_src1 = (const float*)d_in[4];
    const float* att_dst1 = (const float*)d_in[5];
    const float* b1       = (const float*)d_in[6];
    const float* W2       = (const float*)d_in[7];
    const float* att_src2 = (const float*)d_in[8];
    const float* att_dst2 = (const float*)d_in[9];
    const float* b2       = (const float*)d_in[10];
    const float* p2w      = (const float*)d_in[13];
    const float* p2b      = (const float*)d_in[14];
    const float* ln_g     = (const float*)d_in[15];
    const float* ln_b     = (const float*)d_in[16];
    const float* fw1      = (const float*)d_in[17];
    const float* fb1      = (const float*)d_in[18];
    const float* fw2      = (const float*)d_in[19];
    const float* fb2      = (const float*)d_in[20];
    const float* fw3      = (const float*)d_in[21];
    const float* fb3      = (const float*)d_in[22];
    const float* fw4      = (const float*)d_in[23];
    const float* fb4      = (const float*)d_in[24];
    const float* lw       = (const float*)d_in[25];
    const float* lb       = (const float*)d_in[26];
    float* out = (float*)d_out;

    // workspace layout (bytes), ~54 MB total
    char* w = (char*)d_ws;
    ushort* xb   = (ushort*)(w);                 // 32 MB; later h1b(@0)+h2b(@16M)
    ushort* h1b  = (ushort*)(w);
    ushort* h2b  = (ushort*)(w + 16777216);
    ushort* hpre = (ushort*)(w + 33554432);      // 16 MB bf16 GEMM out
    ushort* W1T  = (ushort*)(w + 50331648);      // 1 MB
    ushort* W2T  = (ushort*)(w + 51380224);      // 0.5 MB
    float* asb   = (float*)(w + 51904512);
    float* adb   = (float*)(w + 52166656);
    int*   deg   = (int*)  (w + 52428800);
    int*   cursor= (int*)  (w + 52494336);
    int*   offs  = (int*)  (w + 52559872);
    int*   csr   = (int*)  (w + 52625664);
    float* x2b   = (float*)(w + 53739776);       // 64 KB
    float* xnb   = (float*)(w + 53805056);       // 64 KB
    float* e1b   = (float*)(w + 53870592);       // 32 KB
    float* e2b   = (float*)(w + 53903360);       // 16 KB
    float* e3b   = (float*)(w + 53919744);       // 8 KB

    // ---- CSR build ----
    k_zero_i <<<(2 * NN + 255) / 256, 256, 0, stream>>>(deg, 2 * NN);
    k_degree <<<(EP_ + 255) / 256, 256, 0, stream>>>(ei, deg);
    k_scan   <<<1, 1024, 0, stream>>>(deg, offs);
    k_scatter<<<(EP_ + 255) / 256, 256, 0, stream>>>(ei, offs, cursor, csr);

    // ---- casts ----
    k_cast_x<<<NN * DIN / 4 / 256, 256, 0, stream>>>(x, xb);
    k_castT <<<DIN * HCdim / 4 / 256, 256, 0, stream>>>(W1, W1T, DIN, HCdim, 8);
    k_castT <<<HCdim * HCdim / 4 / 256, 256, 0, stream>>>(W2, W2T, HCdim, HCdim, 7);

    dim3 ggrid(HCdim / 128, NN / 128);
    // ---- GAT layer 1 ----
    gemm_bf16         <<<ggrid, 256, 0, stream>>>(xb, W1T, hpre, NN, HCdim, DIN);
    k_alpha           <<<NN * NHEAD / 4, 256, 0, stream>>>(hpre, att_src1, att_dst1, asb, adb);
    k_aggregate<false><<<NN, 128, 0, stream>>>(hpre, offs, csr, asb, adb, b1, h1b,
                                               nullptr, nullptr, nullptr);
    // ---- GAT layer 2 (pool fused) ----
    gemm_bf16         <<<ggrid, 256, 0, stream>>>(h1b, W2T, hpre, NN, HCdim, HCdim);
    k_alpha           <<<NN * NHEAD / 4, 256, 0, stream>>>(hpre, att_src2, att_dst2, asb, adb);
    k_aggregate<true> <<<NN, 128, 0, stream>>>(hpre, offs, csr, asb, adb, b2, h2b,
                                               p2w, p2b, x2b);
    // ---- layernorm + encoder MLP ----
    k_ln              <<<16, 256, 0, stream>>>(x2b, ln_g, ln_b, xnb, out);
    k_fc<1024, 512>   <<<dim3(8, 16), 256, 0, stream>>>(xnb, fw1, fb1, e1b);
    k_fc< 512, 256>   <<<dim3(4, 16), 256, 0, stream>>>(e1b, fw2, fb2, e2b);
    k_fc< 256, 128>   <<<dim3(2, 16), 256, 0, stream>>>(e2b, fw3, fb3, e3b);
    k_fc_final        <<<16, 256, 0, stream>>>(e3b, fw4, fb4, lw, lb, out);
}

// Round 4
// 392.458 us; speedup vs baseline: 2.0407x; 1.0113x over previous
//
#include <hip/hip_runtime.h>
#include <math.h>

#define NN    16384     // nodes
#define DIN   1024
#define HCdim 512       // H*C
#define NHEAD 4
#define NE_   262144    // edges (without self loops)
#define EP_   (NE_ + NN) // with self loops

using short8  = __attribute__((ext_vector_type(8))) short;
using floatx4 = __attribute__((ext_vector_type(4))) float;

typedef __attribute__((address_space(3))) unsigned int lds_uint;
typedef const __attribute__((address_space(1))) unsigned int glb_uint;
#define ASYNC_LD16(g, l) __builtin_amdgcn_global_load_lds((glb_uint*)(g), (lds_uint*)(l), 16, 0, 0)

__device__ __forceinline__ float eluf(float x){ return x > 0.f ? x : expm1f(x); }
__device__ __forceinline__ float lrelu(float x){ return x > 0.f ? x : 0.2f * x; }
__device__ __forceinline__ float bf2f(unsigned short u){
    union { unsigned int i; float f; } c; c.i = ((unsigned int)u) << 16; return c.f;
}
__device__ __forceinline__ unsigned short f2b(float f){
    union { float f; unsigned int u; } c; c.f = f;
    unsigned int u = c.u;
    return (unsigned short)((u + 0x7FFFu + ((u >> 16) & 1u)) >> 16);   // RNE
}

// ---------------- CSR build ----------------
__global__ void k_zero_i(int* __restrict__ p, int n){
    int i = blockIdx.x * 256 + threadIdx.x;
    if (i < n) p[i] = 0;
}

__global__ void k_degree(const int* __restrict__ ei, int* __restrict__ deg){
    int i = blockIdx.x * 256 + threadIdx.x;
    if (i >= EP_) return;
    int d = (i < NE_) ? ei[NE_ + i] : (i - NE_);
    atomicAdd(&deg[d], 1);
}

__global__ __launch_bounds__(1024) void k_scan(const int* __restrict__ deg, int* __restrict__ offs){
    __shared__ int s[1024];
    int tid  = threadIdx.x;
    int base = tid * 16;
    int local[16];
    int sum = 0;
    #pragma unroll
    for (int i = 0; i < 16; i++){ local[i] = deg[base + i]; sum += local[i]; }
    s[tid] = sum;
    __syncthreads();
    for (int off = 1; off < 1024; off <<= 1){
        int v = (tid >= off) ? s[tid - off] : 0;
        __syncthreads();
        s[tid] += v;
        __syncthreads();
    }
    int run = (tid == 0) ? 0 : s[tid - 1];
    #pragma unroll
    for (int i = 0; i < 16; i++){ offs[base + i] = run; run += local[i]; }
    if (tid == 1023) offs[NN] = run;
}

__global__ void k_scatter(const int* __restrict__ ei, const int* __restrict__ offs,
                          int* __restrict__ cursor, int* __restrict__ csr){
    int i = blockIdx.x * 256 + threadIdx.x;
    if (i >= EP_) return;
    int srcv, dstv;
    if (i < NE_){ srcv = ei[i]; dstv = ei[NE_ + i]; }
    else        { srcv = dstv = i - NE_; }
    int pos = offs[dstv] + atomicAdd(&cursor[dstv], 1);
    csr[pos] = srcv;
}

// ---------------- casts ----------------
__global__ __launch_bounds__(256) void k_cast_x(const float* __restrict__ x, ushort* __restrict__ xb){
    int i = blockIdx.x * 256 + threadIdx.x;
    float4 v = *(const float4*)(x + (size_t)i * 4);
    ushort4 o = { f2b(v.x), f2b(v.y), f2b(v.z), f2b(v.w) };
    *(ushort4*)(xb + (size_t)i * 4) = o;
}

// W[K][Nn] fp32 -> WT[Nn][K] bf16 ;  kshift = log2(K/4)
__global__ __launch_bounds__(256) void k_castT(const float* __restrict__ W, ushort* __restrict__ WT,
                                               int K, int Nn, int kshift){
    int t  = blockIdx.x * 256 + threadIdx.x;
    int n  = t >> kshift;
    int kb = (t & ((1 << kshift) - 1)) * 4;
    ushort4 o;
    o.x = f2b(W[(size_t)(kb + 0) * Nn + n]);
    o.y = f2b(W[(size_t)(kb + 1) * Nn + n]);
    o.z = f2b(W[(size_t)(kb + 2) * Nn + n]);
    o.w = f2b(W[(size_t)(kb + 3) * Nn + n]);
    *(ushort4*)(WT + (size_t)n * K + kb) = o;
}

// ---------------- bf16 MFMA GEMM: C[M,Nn] = A[M,K] @ BT[Nn,K]^T ----------------
// 128x128 tile, BK=32, global_load_lds width-16 staging (m97 2-barrier structure).
__global__ __launch_bounds__(256) void gemm_bf16(const ushort* __restrict__ A,
                                                 const ushort* __restrict__ BT,
                                                 ushort* __restrict__ C,
                                                 int M, int Nn, int K){
    __shared__ ushort As[128 * 32];
    __shared__ ushort Bs[128 * 32];
    int tid = threadIdx.x;
    int m0 = blockIdx.y * 128, n0 = blockIdx.x * 128;
    int lane = tid & 63, w = tid >> 6;
    int wm = (w >> 1) * 64, wn = (w & 1) * 64;
    int la = lane & 15, qd = lane >> 4;

    // staging: thread t covers row=(t>>2)+{0,64}, k-chunk=(t&3)*8 ushorts (16B)
    // LDS dest offset = tid*16 B -> wave-uniform base + lane*16 (global_load_lds constraint OK)
    int srow = tid >> 2, schunk = (tid & 3) * 8;
    const ushort* Ag = A  + (size_t)(m0 + srow) * K + schunk;
    const ushort* Bg = BT + (size_t)(n0 + srow) * K + schunk;
    ushort* Asw = &As[srow * 32 + schunk];
    ushort* Bsw = &Bs[srow * 32 + schunk];

    floatx4 acc[4][4] = {};
    for (int k0 = 0; k0 < K; k0 += 32){
        __syncthreads();   // all waves done reading LDS from previous iter
        ASYNC_LD16(Ag + k0,                  Asw);
        ASYNC_LD16(Ag + (size_t)64 * K + k0, Asw + 64 * 32);
        ASYNC_LD16(Bg + k0,                  Bsw);
        ASYNC_LD16(Bg + (size_t)64 * K + k0, Bsw + 64 * 32);
        __syncthreads();   // drains vmcnt(0): LDS staging complete
        short8 af[4], bf[4];
        #pragma unroll
        for (int i = 0; i < 4; i++){
            af[i] = *(const short8*)&As[(wm + i*16 + la) * 32 + qd * 8];
            bf[i] = *(const short8*)&Bs[(wn + i*16 + la) * 32 + qd * 8];
        }
        #pragma unroll
        for (int i = 0; i < 4; i++)
            #pragma unroll
            for (int j = 0; j < 4; j++)
                acc[i][j] = __builtin_amdgcn_mfma_f32_16x16x32_bf16(af[i], bf[j], acc[i][j], 0, 0, 0);
    }
    // C/D layout: col = lane&15, row = qd*4 + r  (m89/m91-verified)
    #pragma unroll
    for (int i = 0; i < 4; i++)
        #pragma unroll
        for (int j = 0; j < 4; j++){
            int col = n0 + wn + j * 16 + la;
            #pragma unroll
            for (int r = 0; r < 4; r++){
                int row = m0 + wm + i * 16 + qd * 4 + r;
                C[(size_t)row * Nn + col] = f2b(acc[i][j][r]);
            }
        }
}

// ---------------- attention scalars: as/ad [N,4] from bf16 h ----------------
__global__ __launch_bounds__(256) void k_alpha(const ushort* __restrict__ h,
    const float* __restrict__ att_s, const float* __restrict__ att_d,
    float* __restrict__ as_, float* __restrict__ ad_){
    int gt   = blockIdx.x * 256 + threadIdx.x;
    int wid  = gt >> 6;
    int lane = threadIdx.x & 63;
    int n = wid >> 2, hh = wid & 3;
    unsigned int hv = *(const unsigned int*)(h + (size_t)n * HCdim + hh * 128 + lane * 2);
    float h0 = bf2f(hv & 0xffff), h1 = bf2f(hv >> 16);
    float2 sv = *(const float2*)(att_s + hh * 128 + lane * 2);
    float2 dv = *(const float2*)(att_d + hh * 128 + lane * 2);
    float ss = h0 * sv.x + h1 * sv.y;
    float sd = h0 * dv.x + h1 * dv.y;
    #pragma unroll
    for (int off = 32; off; off >>= 1){ ss += __shfl_down(ss, off); sd += __shfl_down(sd, off); }
    if (lane == 0){ as_[n * 4 + hh] = ss; ad_[n * 4 + hh] = sd; }
}

// ---------------- single-pass aggregation: one wave per node, unnormalized accumulate ----------------
// out[n] = elu( (sum_j e_j * h[src_j]) / (sum_j e_j) + bias ),  e_j = exp(lrelu(as[src]+ad[n]))
// Softmax normalization is a post-scale -> no second pass, no barriers, no LDS.
// lane covers channels [lane*8, lane*8+8); head = lane>>4; dsum held redundantly per head group.
template<bool POOL>
__global__ __launch_bounds__(256) void k_aggregate(const ushort* __restrict__ h,
    const int* __restrict__ offs, const int* __restrict__ csr,
    const float* __restrict__ as_, const float* __restrict__ ad_,
    const float* __restrict__ bias, ushort* __restrict__ out,
    const float* __restrict__ pw, const float* __restrict__ pb, float* __restrict__ x2){
    int wv   = threadIdx.x >> 6;
    int lane = threadIdx.x & 63;
    int n    = blockIdx.x * 4 + wv;
    int head = lane >> 4;
    int start = offs[n], end = offs[n + 1];
    float adh = ad_[n * 4 + head];
    float dsum = 0.f;
    float a0=0.f,a1=0.f,a2=0.f,a3=0.f,a4=0.f,a5=0.f,a6=0.f,a7=0.f;
    for (int j = start; j < end; j++){
        int s = csr[j];
        float wgt = __expf(lrelu(as_[s * 4 + head] + adh));
        dsum += wgt;
        uint4 hv = *(const uint4*)(h + (size_t)s * HCdim + lane * 8);
        a0 = fmaf(wgt, bf2f(hv.x & 0xffff), a0);
        a1 = fmaf(wgt, bf2f(hv.x >> 16),    a1);
        a2 = fmaf(wgt, bf2f(hv.y & 0xffff), a2);
        a3 = fmaf(wgt, bf2f(hv.y >> 16),    a3);
        a4 = fmaf(wgt, bf2f(hv.z & 0xffff), a4);
        a5 = fmaf(wgt, bf2f(hv.z >> 16),    a5);
        a6 = fmaf(wgt, bf2f(hv.w & 0xffff), a6);
        a7 = fmaf(wgt, bf2f(hv.w >> 16),    a7);
    }
    float rden = 1.f / (dsum + 1e-16f);
    float4 b0 = *(const float4*)(bias + lane * 8);
    float4 b1 = *(const float4*)(bias + lane * 8 + 4);
    float e0 = eluf(fmaf(a0, rden, b0.x));
    float e1 = eluf(fmaf(a1, rden, b0.y));
    float e2 = eluf(fmaf(a2, rden, b0.z));
    float e3 = eluf(fmaf(a3, rden, b0.w));
    float e4 = eluf(fmaf(a4, rden, b1.x));
    float e5 = eluf(fmaf(a5, rden, b1.y));
    float e6 = eluf(fmaf(a6, rden, b1.z));
    float e7 = eluf(fmaf(a7, rden, b1.w));
    uint4 o;
    o.x = (unsigned)f2b(e0) | ((unsigned)f2b(e1) << 16);
    o.y = (unsigned)f2b(e2) | ((unsigned)f2b(e3) << 16);
    o.z = (unsigned)f2b(e4) | ((unsigned)f2b(e5) << 16);
    o.w = (unsigned)f2b(e6) | ((unsigned)f2b(e7) << 16);
    *(uint4*)(out + (size_t)n * HCdim + lane * 8) = o;
    if (POOL){
        float4 w0 = *(const float4*)(pw + lane * 8);
        float4 w1 = *(const float4*)(pw + lane * 8 + 4);
        float s = e0*w0.x + e1*w0.y + e2*w0.z + e3*w0.w
                + e4*w1.x + e5*w1.y + e6*w1.z + e7*w1.w;
        #pragma unroll
        for (int off = 32; off; off >>= 1) s += __shfl_down(s, off);
        if (lane == 0) x2[n] = s + pb[0];
    }
}

// ---------------- layernorm: x2 [16,1024] -> xn (ws) + multiscale out ----------------
__global__ __launch_bounds__(256) void k_ln(const float* __restrict__ x2,
    const float* __restrict__ lng, const float* __restrict__ lnb,
    float* __restrict__ xnb, float* __restrict__ out){
    __shared__ float red[8];
    __shared__ float stats[2];
    int b = blockIdx.x, tid = threadIdx.x;
    float4 v = *(const float4*)(x2 + b * 1024 + tid * 4);
    float s  = v.x + v.y + v.z + v.w;
    float sq = v.x * v.x + v.y * v.y + v.z * v.z + v.w * v.w;
    #pragma unroll
    for (int off = 32; off; off >>= 1){ s += __shfl_down(s, off); sq += __shfl_down(sq, off); }
    if ((tid & 63) == 0){ red[(tid >> 6) * 2] = s; red[(tid >> 6) * 2 + 1] = sq; }
    __syncthreads();
    if (tid == 0){
        float S  = red[0] + red[2] + red[4] + red[6];
        float SQ = red[1] + red[3] + red[5] + red[7];
        float mu  = S * (1.f / 1024.f);
        float var = SQ * (1.f / 1024.f) - mu * mu;
        stats[0] = mu; stats[1] = rsqrtf(var + 1e-5f);
    }
    __syncthreads();
    float mu = stats[0], r = stats[1];
    float4 g4  = *(const float4*)(lng + tid * 4);
    float4 bb4 = *(const float4*)(lnb + tid * 4);
    float4 o;
    o.x = (v.x - mu) * r * g4.x + bb4.x;
    o.y = (v.y - mu) * r * g4.y + bb4.y;
    o.z = (v.z - mu) * r * g4.z + bb4.z;
    o.w = (v.w - mu) * r * g4.w + bb4.w;
    *(float4*)(xnb + b * 1024 + tid * 4) = o;
    *(float4*)(out + b * 1024 + tid * 4) = o;
}

// ---------------- FC layer: out[b, c] = elu(in[b,:] . W[:,c] + bias[c]) ----------------
template<int K, int NOUT>
__global__ __launch_bounds__(256) void k_fc(const float* __restrict__ in,
    const float* __restrict__ W, const float* __restrict__ bias, float* __restrict__ outb){
    __shared__ float xs[K];
    __shared__ float red[4][64];
    int tid = threadIdx.x;
    int b = blockIdx.y, c0 = blockIdx.x * 64;
    int tx = tid & 63, ty = tid >> 6;
    for (int i = tid * 4; i < K; i += 1024)
        *(float4*)&xs[i] = *(const float4*)(in + b * K + i);
    __syncthreads();
    const float* wp = W + (size_t)(ty * (K / 4)) * NOUT + c0 + tx;
    float a = 0.f;
    #pragma unroll 8
    for (int i = 0; i < K / 4; i++)
        a = fmaf(xs[ty * (K / 4) + i], wp[(size_t)i * NOUT], a);
    red[ty][tx] = a;
    __syncthreads();
    if (ty == 0){
        float v = red[0][tx] + red[1][tx] + red[2][tx] + red[3][tx] + bias[c0 + tx];
        outb[b * NOUT + tx + c0] = eluf(v);
    }
}

// ---------------- final FC (128->64) + e output + pred ----------------
__global__ __launch_bounds__(256) void k_fc_final(const float* __restrict__ in,
    const float* __restrict__ W, const float* __restrict__ bias,
    const float* __restrict__ lw, const float* __restrict__ lb, float* __restrict__ out){
    __shared__ float xs[128];
    __shared__ float red[4][64];
    __shared__ float evs[64];
    int tid = threadIdx.x;
    int b = blockIdx.x;
    int tx = tid & 63, ty = tid >> 6;
    if (tid * 4 < 128)
        *(float4*)&xs[tid * 4] = *(const float4*)(in + b * 128 + tid * 4);
    __syncthreads();
    const float* wp = W + (size_t)(ty * 32) * 64 + tx;
    float a = 0.f;
    #pragma unroll
    for (int i = 0; i < 32; i++)
        a = fmaf(xs[ty * 32 + i], wp[(size_t)i * 64], a);
    red[ty][tx] = a;
    __syncthreads();
    if (ty == 0){
        float ev = eluf(red[0][tx] + red[1][tx] + red[2][tx] + red[3][tx] + bias[tx]);
        evs[tx] = ev;
        out[16384 + b * 64 + tx] = ev;
    }
    __syncthreads();
    if (ty == 0){
        float p = evs[tx] * lw[tx];
        #pragma unroll
        for (int off = 32; off; off >>= 1) p += __shfl_down(p, off);
        if (tx == 0) out[16384 + 1024 + b] = p + lb[0];
    }
}

extern "C" void kernel_launch(void* const* d_in, const int* in_sizes, int n_in,
                              void* d_out, int out_size, void* d_ws, size_t ws_size,
                              hipStream_t stream) {
    const float* x        = (const float*)d_in[0];
    const int*   ei       = (const int*)  d_in[1];
    const float* W1       = (const float*)d_in[3];
    const float* att_src1 = (const float*)d_in[4];
    const float* att_dst1 = (const float*)d_in[5];
    const float* b1       = (const float*)d_in[6];
    const float* W2       = (const float*)d_in[7];
    const float* att_src2 = (const float*)d_in[8];
    const float* att_dst2 = (const float*)d_in[9];
    const float* b2       = (const float*)d_in[10];
    const float* p2w      = (const float*)d_in[13];
    const float* p2b      = (const float*)d_in[14];
    const float* ln_g     = (const float*)d_in[15];
    const float* ln_b     = (const float*)d_in[16];
    const float* fw1      = (const float*)d_in[17];
    const float* fb1      = (const float*)d_in[18];
    const float* fw2      = (const float*)d_in[19];
    const float* fb2      = (const float*)d_in[20];
    const float* fw3      = (const float*)d_in[21];
    const float* fb3      = (const float*)d_in[22];
    const float* fw4      = (const float*)d_in[23];
    const float* fb4      = (const float*)d_in[24];
    const float* lw       = (const float*)d_in[25];
    const float* lb       = (const float*)d_in[26];
    float* out = (float*)d_out;

    // workspace layout (bytes), ~54 MB total
    char* w = (char*)d_ws;
    ushort* xb   = (ushort*)(w);                 // 32 MB; later h1b(@0)+h2b(@16M)
    ushort* h1b  = (ushort*)(w);
    ushort* h2b  = (ushort*)(w + 16777216);
    ushort* hpre = (ushort*)(w + 33554432);      // 16 MB bf16 GEMM out
    ushort* W1T  = (ushort*)(w + 50331648);      // 1 MB
    ushort* W2T  = (ushort*)(w + 51380224);      // 0.5 MB
    float* asb   = (float*)(w + 51904512);
    float* adb   = (float*)(w + 52166656);
    int*   deg   = (int*)  (w + 52428800);
    int*   cursor= (int*)  (w + 52494336);
    int*   offs  = (int*)  (w + 52559872);
    int*   csr   = (int*)  (w + 52625664);
    float* x2b   = (float*)(w + 53739776);       // 64 KB
    float* xnb   = (float*)(w + 53805056);       // 64 KB
    float* e1b   = (float*)(w + 53870592);       // 32 KB
    float* e2b   = (float*)(w + 53903360);       // 16 KB
    float* e3b   = (float*)(w + 53919744);       // 8 KB

    // ---- CSR build ----
    k_zero_i <<<(2 * NN + 255) / 256, 256, 0, stream>>>(deg, 2 * NN);
    k_degree <<<(EP_ + 255) / 256, 256, 0, stream>>>(ei, deg);
    k_scan   <<<1, 1024, 0, stream>>>(deg, offs);
    k_scatter<<<(EP_ + 255) / 256, 256, 0, stream>>>(ei, offs, cursor, csr);

    // ---- casts ----
    k_cast_x<<<NN * DIN / 4 / 256, 256, 0, stream>>>(x, xb);
    k_castT <<<DIN * HCdim / 4 / 256, 256, 0, stream>>>(W1, W1T, DIN, HCdim, 8);
    k_castT <<<HCdim * HCdim / 4 / 256, 256, 0, stream>>>(W2, W2T, HCdim, HCdim, 7);

    dim3 ggrid(HCdim / 128, NN / 128);
    // ---- GAT layer 1 ----
    gemm_bf16         <<<ggrid, 256, 0, stream>>>(xb, W1T, hpre, NN, HCdim, DIN);
    k_alpha           <<<NN * NHEAD / 4, 256, 0, stream>>>(hpre, att_src1, att_dst1, asb, adb);
    k_aggregate<false><<<NN / 4, 256, 0, stream>>>(hpre, offs, csr, asb, adb, b1, h1b,
                                                   nullptr, nullptr, nullptr);
    // ---- GAT layer 2 (pool fused) ----
    gemm_bf16         <<<ggrid, 256, 0, stream>>>(h1b, W2T, hpre, NN, HCdim, HCdim);
    k_alpha           <<<NN * NHEAD / 4, 256, 0, stream>>>(hpre, att_src2, att_dst2, asb, adb);
    k_aggregate<true> <<<NN / 4, 256, 0, stream>>>(hpre, offs, csr, asb, adb, b2, h2b,
                                                   p2w, p2b, x2b);
    // ---- layernorm + encoder MLP ----
    k_ln              <<<16, 256, 0, stream>>>(x2b, ln_g, ln_b, xnb, out);
    k_fc<1024, 512>   <<<dim3(8, 16), 256, 0, stream>>>(xnb, fw1, fb1, e1b);
    k_fc< 512, 256>   <<<dim3(4, 16), 256, 0, stream>>>(e1b, fw2, fb2, e2b);
    k_fc< 256, 128>   <<<dim3(2, 16), 256, 0, stream>>>(e2b, fw3, fb3, e3b);
    k_fc_final        <<<16, 256, 0, stream>>>(e3b, fw4, fb4, lw, lb, out);
}

// Round 5
// 376.011 us; speedup vs baseline: 2.1300x; 1.0437x over previous
//
#include <hip/hip_runtime.h>
#include <math.h>

#define NN    16384     // nodes
#define DIN   1024
#define HCdim 512       // H*C
#define NHEAD 4
#define NE_   262144    // edges (without self loops)
#define EP_   (NE_ + NN) // with self loops

using short8  = __attribute__((ext_vector_type(8))) short;
using floatx4 = __attribute__((ext_vector_type(4))) float;

typedef __attribute__((address_space(3))) unsigned int lds_uint;
typedef const __attribute__((address_space(1))) unsigned int glb_uint;
#define ASYNC_LD16(g, l) __builtin_amdgcn_global_load_lds((glb_uint*)(g), (lds_uint*)(l), 16, 0, 0)

__device__ __forceinline__ float eluf(float x){ return x > 0.f ? x : expm1f(x); }
__device__ __forceinline__ float lrelu(float x){ return x > 0.f ? x : 0.2f * x; }
__device__ __forceinline__ float bf2f(unsigned short u){
    union { unsigned int i; float f; } c; c.i = ((unsigned int)u) << 16; return c.f;
}
__device__ __forceinline__ unsigned short f2b(float f){
    union { float f; unsigned int u; } c; c.f = f;
    unsigned int u = c.u;
    return (unsigned short)((u + 0x7FFFu + ((u >> 16) & 1u)) >> 16);   // RNE
}

// ---------------- CSR build ----------------
__global__ void k_zero_i(int* __restrict__ p, int n){
    int i = blockIdx.x * 256 + threadIdx.x;
    if (i < n) p[i] = 0;
}

__global__ void k_degree(const int* __restrict__ ei, int* __restrict__ deg){
    int i = blockIdx.x * 256 + threadIdx.x;
    if (i >= EP_) return;
    int d = (i < NE_) ? ei[NE_ + i] : (i - NE_);
    atomicAdd(&deg[d], 1);
}

__global__ __launch_bounds__(1024) void k_scan(const int* __restrict__ deg, int* __restrict__ offs){
    __shared__ int s[1024];
    int tid  = threadIdx.x;
    int base = tid * 16;
    int local[16];
    int sum = 0;
    #pragma unroll
    for (int i = 0; i < 16; i++){ local[i] = deg[base + i]; sum += local[i]; }
    s[tid] = sum;
    __syncthreads();
    for (int off = 1; off < 1024; off <<= 1){
        int v = (tid >= off) ? s[tid - off] : 0;
        __syncthreads();
        s[tid] += v;
        __syncthreads();
    }
    int run = (tid == 0) ? 0 : s[tid - 1];
    #pragma unroll
    for (int i = 0; i < 16; i++){ offs[base + i] = run; run += local[i]; }
    if (tid == 1023) offs[NN] = run;
}

__global__ void k_scatter(const int* __restrict__ ei, const int* __restrict__ offs,
                          int* __restrict__ cursor, int* __restrict__ csr){
    int i = blockIdx.x * 256 + threadIdx.x;
    if (i >= EP_) return;
    int srcv, dstv;
    if (i < NE_){ srcv = ei[i]; dstv = ei[NE_ + i]; }
    else        { srcv = dstv = i - NE_; }
    int pos = offs[dstv] + atomicAdd(&cursor[dstv], 1);
    csr[pos] = srcv;
}

// ---------------- merged casts: x -> bf16 ; W1,W2 -> bf16 transposed ----------------
__global__ __launch_bounds__(256) void k_casts(const float* __restrict__ x, ushort* __restrict__ xb,
    const float* __restrict__ W1, ushort* __restrict__ W1T,
    const float* __restrict__ W2, ushort* __restrict__ W2T){
    int bid = blockIdx.x, tid = threadIdx.x;
    if (bid < 16384){
        int i = bid * 256 + tid;
        float4 v = *(const float4*)(x + (size_t)i * 4);
        ushort4 o = { f2b(v.x), f2b(v.y), f2b(v.z), f2b(v.w) };
        *(ushort4*)(xb + (size_t)i * 4) = o;
    } else if (bid < 16384 + 512){
        int t = (bid - 16384) * 256 + tid;          // W1: 1024x512 -> T
        int n = t >> 8, kb = (t & 255) * 4;
        ushort4 o = { f2b(W1[(size_t)(kb+0)*HCdim + n]), f2b(W1[(size_t)(kb+1)*HCdim + n]),
                      f2b(W1[(size_t)(kb+2)*HCdim + n]), f2b(W1[(size_t)(kb+3)*HCdim + n]) };
        *(ushort4*)(W1T + (size_t)n * DIN + kb) = o;
    } else {
        int t = (bid - 16896) * 256 + tid;          // W2: 512x512 -> T
        int n = t >> 7, kb = (t & 127) * 4;
        ushort4 o = { f2b(W2[(size_t)(kb+0)*HCdim + n]), f2b(W2[(size_t)(kb+1)*HCdim + n]),
                      f2b(W2[(size_t)(kb+2)*HCdim + n]), f2b(W2[(size_t)(kb+3)*HCdim + n]) };
        *(ushort4*)(W2T + (size_t)n * HCdim + kb) = o;
    }
}

// ---------------- bf16 MFMA GEMM + fused attention-scalar epilogue ----------------
// C[M,512] = A[M,K] @ BT[512,K]^T. 128x128 tile => blockIdx.x == head (512/128=4).
// Epilogue: as_[n*4+head] = sum_c h[n, head*128+c]*att_s[head][c] (fp32 acc, pre-bias as in ref).
__global__ __launch_bounds__(256) void gemm_bf16(const ushort* __restrict__ A,
                                                 const ushort* __restrict__ BT,
                                                 ushort* __restrict__ C,
                                                 const float* __restrict__ att_s,
                                                 const float* __restrict__ att_d,
                                                 float* __restrict__ as_, float* __restrict__ ad_,
                                                 int M, int Nn, int K){
    __shared__ ushort As[128 * 32];
    __shared__ ushort Bs[128 * 32];
    __shared__ float prS[2][128];
    __shared__ float prD[2][128];
    int tid = threadIdx.x;
    int m0 = blockIdx.y * 128, n0 = blockIdx.x * 128;
    int cx = blockIdx.x;                 // head
    int lane = tid & 63, w = tid >> 6;
    int wm = (w >> 1) * 64, wn = (w & 1) * 64;
    int la = lane & 15, qd = lane >> 4;

    int srow = tid >> 2, schunk = (tid & 3) * 8;
    const ushort* Ag = A  + (size_t)(m0 + srow) * K + schunk;
    const ushort* Bg = BT + (size_t)(n0 + srow) * K + schunk;
    ushort* Asw = &As[srow * 32 + schunk];
    ushort* Bsw = &Bs[srow * 32 + schunk];

    floatx4 acc[4][4] = {};
    for (int k0 = 0; k0 < K; k0 += 32){
        __syncthreads();
        ASYNC_LD16(Ag + k0,                  Asw);
        ASYNC_LD16(Ag + (size_t)64 * K + k0, Asw + 64 * 32);
        ASYNC_LD16(Bg + k0,                  Bsw);
        ASYNC_LD16(Bg + (size_t)64 * K + k0, Bsw + 64 * 32);
        __syncthreads();
        short8 af[4], bf[4];
        #pragma unroll
        for (int i = 0; i < 4; i++){
            af[i] = *(const short8*)&As[(wm + i*16 + la) * 32 + qd * 8];
            bf[i] = *(const short8*)&Bs[(wn + i*16 + la) * 32 + qd * 8];
        }
        #pragma unroll
        for (int i = 0; i < 4; i++)
            #pragma unroll
            for (int j = 0; j < 4; j++)
                acc[i][j] = __builtin_amdgcn_mfma_f32_16x16x32_bf16(af[i], bf[j], acc[i][j], 0, 0, 0);
    }
    // attention partials: lane's att values for its 4 cols (j*16+la within head)
    float asv[4], adv[4];
    #pragma unroll
    for (int j = 0; j < 4; j++){
        asv[j] = att_s[cx * 128 + wn + j * 16 + la];
        adv[j] = att_d[cx * 128 + wn + j * 16 + la];
    }
    int half = wn >> 6;
    #pragma unroll
    for (int i = 0; i < 4; i++){
        #pragma unroll
        for (int r = 0; r < 4; r++){
            float ps = 0.f, pd = 0.f;
            #pragma unroll
            for (int j = 0; j < 4; j++){
                ps = fmaf(acc[i][j][r], asv[j], ps);
                pd = fmaf(acc[i][j][r], adv[j], pd);
            }
            #pragma unroll
            for (int off = 1; off < 16; off <<= 1){
                ps += __shfl_xor(ps, off);   // stays within same qd group (lane bits 0-3)
                pd += __shfl_xor(pd, off);
            }
            if (la == 0){
                int rl = wm + i * 16 + qd * 4 + r;
                prS[half][rl] = ps; prD[half][rl] = pd;
            }
        }
    }
    // C store (bf16), layout col=lane&15, row=qd*4+r (m89/m91-verified)
    #pragma unroll
    for (int i = 0; i < 4; i++)
        #pragma unroll
        for (int j = 0; j < 4; j++){
            int col = n0 + wn + j * 16 + la;
            #pragma unroll
            for (int r = 0; r < 4; r++){
                int row = m0 + wm + i * 16 + qd * 4 + r;
                C[(size_t)row * Nn + col] = f2b(acc[i][j][r]);
            }
        }
    __syncthreads();
    if (tid < 128){
        as_[(size_t)(m0 + tid) * 4 + cx] = prS[0][tid] + prS[1][tid];
        ad_[(size_t)(m0 + tid) * 4 + cx] = prD[0][tid] + prD[1][tid];
    }
}

// ---------------- edge weights: wbuf[j][h] = bf16(exp(lrelu(as[src_j][h] + ad[dst_j][h]))) ----------------
__global__ __launch_bounds__(256) void k_edgew(const int* __restrict__ offs, const int* __restrict__ csr,
    const float* __restrict__ as_, const float* __restrict__ ad_, ushort* __restrict__ wbuf){
    int wv = threadIdx.x >> 6, lane = threadIdx.x & 63;
    int n = blockIdx.x * 4 + wv;
    int start = offs[n], end = offs[n + 1];
    float4 ad4 = *(const float4*)(ad_ + (size_t)n * 4);
    for (int j = start + lane; j < end; j += 64){
        int s = csr[j];
        float4 as4 = *(const float4*)(as_ + (size_t)s * 4);
        ushort4 o = { f2b(__expf(lrelu(as4.x + ad4.x))), f2b(__expf(lrelu(as4.y + ad4.y))),
                      f2b(__expf(lrelu(as4.z + ad4.z))), f2b(__expf(lrelu(as4.w + ad4.w))) };
        *(ushort4*)(wbuf + (size_t)j * 4) = o;
    }
}

// ---------------- single-pass aggregation, depth-2 software pipeline ----------------
// one wave per node; lane covers channels [lane*8, lane*8+8); head = lane>>4.
// out[n] = elu((sum_j w_j*h[src_j]) / (sum_j w_j) + bias); w precomputed in wbuf.
#define AGG_CONSUME(WS, HV)                                  \
    { float wgt = bf2f(WS);                                  \
      dsum += wgt;                                           \
      a0 = fmaf(wgt, bf2f(HV.x & 0xffff), a0);               \
      a1 = fmaf(wgt, bf2f(HV.x >> 16),    a1);               \
      a2 = fmaf(wgt, bf2f(HV.y & 0xffff), a2);               \
      a3 = fmaf(wgt, bf2f(HV.y >> 16),    a3);               \
      a4 = fmaf(wgt, bf2f(HV.z & 0xffff), a4);               \
      a5 = fmaf(wgt, bf2f(HV.z >> 16),    a5);               \
      a6 = fmaf(wgt, bf2f(HV.w & 0xffff), a6);               \
      a7 = fmaf(wgt, bf2f(HV.w >> 16),    a7); }

template<bool POOL>
__global__ __launch_bounds__(256) void k_aggregate(const ushort* __restrict__ h,
    const int* __restrict__ offs, const int* __restrict__ csr,
    const ushort* __restrict__ wbuf,
    const float* __restrict__ bias, ushort* __restrict__ out,
    const float* __restrict__ pw, const float* __restrict__ pb, float* __restrict__ x2){
    int wv   = threadIdx.x >> 6;
    int lane = threadIdx.x & 63;
    int n    = blockIdx.x * 4 + wv;
    int head = lane >> 4;
    int start = offs[n], end = offs[n + 1];
    float dsum = 0.f;
    float a0=0.f,a1=0.f,a2=0.f,a3=0.f,a4=0.f,a5=0.f,a6=0.f,a7=0.f;
    for (int base = start; base < end; base += 64){
        int cnt = min(64, end - base);
        int pre = (base + lane < end) ? csr[base + lane] : 0;   // 64 indices staged in regs
        // pipeline prologue (cnt >= 1 always: self-loops guarantee deg >= 1)
        int s0 = __builtin_amdgcn_readlane(pre, 0);
        ushort w0 = wbuf[(size_t)base * 4 + head];
        uint4  h0 = *(const uint4*)(h + (size_t)s0 * HCdim + lane * 8);
        ushort w1 = 0; uint4 h1 = {0,0,0,0};
        if (cnt > 1){
            int s1 = __builtin_amdgcn_readlane(pre, 1);
            w1 = wbuf[(size_t)(base + 1) * 4 + head];
            h1 = *(const uint4*)(h + (size_t)s1 * HCdim + lane * 8);
        }
        for (int jj = 0; jj < cnt; jj++){
            ushort w2 = 0; uint4 h2 = {0,0,0,0};
            if (jj + 2 < cnt){
                int s2 = __builtin_amdgcn_readlane(pre, jj + 2);
                w2 = wbuf[(size_t)(base + jj + 2) * 4 + head];
                h2 = *(const uint4*)(h + (size_t)s2 * HCdim + lane * 8);
            }
            AGG_CONSUME(w0, h0);
            w0 = w1; h0 = h1;
            w1 = w2; h1 = h2;
        }
    }
    float rden = 1.f / (dsum + 1e-16f);
    float4 b0 = *(const float4*)(bias + lane * 8);
    float4 b1 = *(const float4*)(bias + lane * 8 + 4);
    float e0 = eluf(fmaf(a0, rden, b0.x));
    float e1 = eluf(fmaf(a1, rden, b0.y));
    float e2 = eluf(fmaf(a2, rden, b0.z));
    float e3 = eluf(fmaf(a3, rden, b0.w));
    float e4 = eluf(fmaf(a4, rden, b1.x));
    float e5 = eluf(fmaf(a5, rden, b1.y));
    float e6 = eluf(fmaf(a6, rden, b1.z));
    float e7 = eluf(fmaf(a7, rden, b1.w));
    uint4 o;
    o.x = (unsigned)f2b(e0) | ((unsigned)f2b(e1) << 16);
    o.y = (unsigned)f2b(e2) | ((unsigned)f2b(e3) << 16);
    o.z = (unsigned)f2b(e4) | ((unsigned)f2b(e5) << 16);
    o.w = (unsigned)f2b(e6) | ((unsigned)f2b(e7) << 16);
    *(uint4*)(out + (size_t)n * HCdim + lane * 8) = o;
    if (POOL){
        float4 w0p = *(const float4*)(pw + lane * 8);
        float4 w1p = *(const float4*)(pw + lane * 8 + 4);
        float s = e0*w0p.x + e1*w0p.y + e2*w0p.z + e3*w0p.w
                + e4*w1p.x + e5*w1p.y + e6*w1p.z + e7*w1p.w;
        #pragma unroll
        for (int off = 32; off; off >>= 1) s += __shfl_down(s, off);
        if (lane == 0) x2[n] = s + pb[0];
    }
}

// ---------------- fc1 with fused layernorm: x2[16,1024] -> LN -> multiscale out + fc1(1024->512) ----------------
__global__ __launch_bounds__(256) void k_fc1_ln(const float* __restrict__ x2,
    const float* __restrict__ lng, const float* __restrict__ lnb,
    const float* __restrict__ W, const float* __restrict__ bias,
    float* __restrict__ outms, float* __restrict__ e1b){
    __shared__ float xs[1024];
    __shared__ float red[4][64];
    __shared__ float red2[8];
    __shared__ float stats[2];
    int tid = threadIdx.x;
    int b = blockIdx.y, c0 = blockIdx.x * 64;
    float4 v = *(const float4*)(x2 + b * 1024 + tid * 4);
    float s  = v.x + v.y + v.z + v.w;
    float sq = v.x * v.x + v.y * v.y + v.z * v.z + v.w * v.w;
    #pragma unroll
    for (int off = 32; off; off >>= 1){ s += __shfl_down(s, off); sq += __shfl_down(sq, off); }
    if ((tid & 63) == 0){ red2[(tid >> 6) * 2] = s; red2[(tid >> 6) * 2 + 1] = sq; }
    __syncthreads();
    if (tid == 0){
        float S  = red2[0] + red2[2] + red2[4] + red2[6];
        float SQ = red2[1] + red2[3] + red2[5] + red2[7];
        float mu  = S * (1.f / 1024.f);
        float var = SQ * (1.f / 1024.f) - mu * mu;
        stats[0] = mu; stats[1] = rsqrtf(var + 1e-5f);
    }
    __syncthreads();
    float mu = stats[0], r = stats[1];
    float4 g4  = *(const float4*)(lng + tid * 4);
    float4 bb4 = *(const float4*)(lnb + tid * 4);
    float4 o;
    o.x = (v.x - mu) * r * g4.x + bb4.x;
    o.y = (v.y - mu) * r * g4.y + bb4.y;
    o.z = (v.z - mu) * r * g4.z + bb4.z;
    o.w = (v.w - mu) * r * g4.w + bb4.w;
    *(float4*)&xs[tid * 4] = o;
    if (blockIdx.x == 0) *(float4*)(outms + b * 1024 + tid * 4) = o;  // multiscale output
    __syncthreads();
    int tx = tid & 63, ty = tid >> 6;
    const float* wp = W + (size_t)(ty * 256) * 512 + c0 + tx;
    float a = 0.f;
    #pragma unroll 8
    for (int i = 0; i < 256; i++)
        a = fmaf(xs[ty * 256 + i], wp[(size_t)i * 512], a);
    red[ty][tx] = a;
    __syncthreads();
    if (ty == 0){
        float vv = red[0][tx] + red[1][tx] + red[2][tx] + red[3][tx] + bias[c0 + tx];
        e1b[b * 512 + c0 + tx] = eluf(vv);
    }
}

// ---------------- FC layer: out[b,c] = elu(in[b,:] . W[:,c] + bias[c]) ----------------
template<int K, int NOUT>
__global__ __launch_bounds__(256) void k_fc(const float* __restrict__ in,
    const float* __restrict__ W, const float* __restrict__ bias, float* __restrict__ outb){
    __shared__ float xs[K];
    __shared__ float red[4][64];
    int tid = threadIdx.x;
    int b = blockIdx.y, c0 = blockIdx.x * 64;
    int tx = tid & 63, ty = tid >> 6;
    for (int i = tid * 4; i < K; i += 1024)
        *(float4*)&xs[i] = *(const float4*)(in + b * K + i);
    __syncthreads();
    const float* wp = W + (size_t)(ty * (K / 4)) * NOUT + c0 + tx;
    float a = 0.f;
    #pragma unroll 8
    for (int i = 0; i < K / 4; i++)
        a = fmaf(xs[ty * (K / 4) + i], wp[(size_t)i * NOUT], a);
    red[ty][tx] = a;
    __syncthreads();
    if (ty == 0){
        float v = red[0][tx] + red[1][tx] + red[2][tx] + red[3][tx] + bias[c0 + tx];
        outb[b * NOUT + tx + c0] = eluf(v);
    }
}

// ---------------- final FC (128->64) + e output + pred ----------------
__global__ __launch_bounds__(256) void k_fc_final(const float* __restrict__ in,
    const float* __restrict__ W, const float* __restrict__ bias,
    const float* __restrict__ lw, const float* __restrict__ lb, float* __restrict__ out){
    __shared__ float xs[128];
    __shared__ float red[4][64];
    __shared__ float evs[64];
    int tid = threadIdx.x;
    int b = blockIdx.x;
    int tx = tid & 63, ty = tid >> 6;
    if (tid * 4 < 128)
        *(float4*)&xs[tid * 4] = *(const float4*)(in + b * 128 + tid * 4);
    __syncthreads();
    const float* wp = W + (size_t)(ty * 32) * 64 + tx;
    float a = 0.f;
    #pragma unroll
    for (int i = 0; i < 32; i++)
        a = fmaf(xs[ty * 32 + i], wp[(size_t)i * 64], a);
    red[ty][tx] = a;
    __syncthreads();
    if (ty == 0){
        float ev = eluf(red[0][tx] + red[1][tx] + red[2][tx] + red[3][tx] + bias[tx]);
        evs[tx] = ev;
        out[16384 + b * 64 + tx] = ev;
    }
    __syncthreads();
    if (ty == 0){
        float p = evs[tx] * lw[tx];
        #pragma unroll
        for (int off = 32; off; off >>= 1) p += __shfl_down(p, off);
        if (tx == 0) out[16384 + 1024 + b] = p + lb[0];
    }
}

extern "C" void kernel_launch(void* const* d_in, const int* in_sizes, int n_in,
                              void* d_out, int out_size, void* d_ws, size_t ws_size,
                              hipStream_t stream) {
    const float* x        = (const float*)d_in[0];
    const int*   ei       = (const int*)  d_in[1];
    const float* W1       = (const float*)d_in[3];
    const float* att_src1 = (const float*)d_in[4];
    const float* att_dst1 = (const float*)d_in[5];
    const float* b1       = (const float*)d_in[6];
    const float* W2       = (const float*)d_in[7];
    const float* att_src2 = (const float*)d_in[8];
    const float* att_dst2 = (const float*)d_in[9];
    const float* b2       = (const float*)d_in[10];
    const float* p2w      = (const float*)d_in[13];
    const float* p2b      = (const float*)d_in[14];
    const float* ln_g     = (const float*)d_in[15];
    const float* ln_b     = (const float*)d_in[16];
    const float* fw1      = (const float*)d_in[17];
    const float* fb1      = (const float*)d_in[18];
    const float* fw2      = (const float*)d_in[19];
    const float* fb2      = (const float*)d_in[20];
    const float* fw3      = (const float*)d_in[21];
    const float* fb3      = (const float*)d_in[22];
    const float* fw4      = (const float*)d_in[23];
    const float* fb4      = (const float*)d_in[24];
    const float* lw       = (const float*)d_in[25];
    const float* lb       = (const float*)d_in[26];
    float* out = (float*)d_out;

    // workspace layout (bytes), ~56.1 MB total
    char* w = (char*)d_ws;
    ushort* xb   = (ushort*)(w);                 // 32 MB; later h1b(@0)+h2b(@16M)
    ushort* h1b  = (ushort*)(w);
    ushort* h2b  = (ushort*)(w + 16777216);
    ushort* hpre = (ushort*)(w + 33554432);      // 16 MB bf16 GEMM out
    ushort* W1T  = (ushort*)(w + 50331648);      // 1 MB
    ushort* W2T  = (ushort*)(w + 51380224);      // 0.5 MB
    float* asb   = (float*)(w + 51904512);       // 256 KB
    float* adb   = (float*)(w + 52166656);       // 256 KB
    int*   deg   = (int*)  (w + 52428800);       // 64 KB
    int*   cursor= (int*)  (w + 52494336);       // 64 KB
    int*   offs  = (int*)  (w + 52559872);       // 64 KB + 4
    int*   csr   = (int*)  (w + 52625664);       // EP_*4 -> ends 53739776
    ushort* wbuf = (ushort*)(w + 53739776);      // EP_*4*2 = 2.23 MB -> ends 55968000
    float* x2b   = (float*)(w + 55968000);       // 64 KB
    float* e1b   = (float*)(w + 56033536);       // 32 KB
    float* e2b   = (float*)(w + 56066304);       // 16 KB
    float* e3b   = (float*)(w + 56082688);       // 8 KB

    // ---- CSR build ----
    k_zero_i <<<(2 * NN + 255) / 256, 256, 0, stream>>>(deg, 2 * NN);
    k_degree <<<(EP_ + 255) / 256, 256, 0, stream>>>(ei, deg);
    k_scan   <<<1, 1024, 0, stream>>>(deg, offs);
    k_scatter<<<(EP_ + 255) / 256, 256, 0, stream>>>(ei, offs, cursor, csr);

    // ---- casts (merged) ----
    k_casts<<<16384 + 512 + 256, 256, 0, stream>>>(x, xb, W1, W1T, W2, W2T);

    dim3 ggrid(HCdim / 128, NN / 128);
    // ---- GAT layer 1 ----
    gemm_bf16         <<<ggrid, 256, 0, stream>>>(xb, W1T, hpre, att_src1, att_dst1,
                                                  asb, adb, NN, HCdim, DIN);
    k_edgew           <<<NN / 4, 256, 0, stream>>>(offs, csr, asb, adb, wbuf);
    k_aggregate<false><<<NN / 4, 256, 0, stream>>>(hpre, offs, csr, wbuf, b1, h1b,
                                                   nullptr, nullptr, nullptr);
    // ---- GAT layer 2 (pool fused) ----
    gemm_bf16         <<<ggrid, 256, 0, stream>>>(h1b, W2T, hpre, att_src2, att_dst2,
                                                  asb, adb, NN, HCdim, HCdim);
    k_edgew           <<<NN / 4, 256, 0, stream>>>(offs, csr, asb, adb, wbuf);
    k_aggregate<true> <<<NN / 4, 256, 0, stream>>>(hpre, offs, csr, wbuf, b2, h2b,
                                                   p2w, p2b, x2b);
    // ---- encoder MLP (LN fused into fc1) ----
    k_fc1_ln          <<<dim3(8, 16), 256, 0, stream>>>(x2b, ln_g, ln_b, fw1, fb1, out, e1b);
    k_fc< 512, 256>   <<<dim3(4, 16), 256, 0, stream>>>(e1b, fw2, fb2, e2b);
    k_fc< 256, 128>   <<<dim3(2, 16), 256, 0, stream>>>(e2b, fw3, fb3, e3b);
    k_fc_final        <<<16, 256, 0, stream>>>(e3b, fw4, fb4, lw, lb, out);
}

// Round 6
// 371.042 us; speedup vs baseline: 2.1585x; 1.0134x over previous
//
#include <hip/hip_runtime.h>
#include <math.h>

#define NN    16384     // nodes
#define DIN   1024
#define HCdim 512       // H*C
#define NHEAD 4
#define NE_   262144    // edges (without self loops)
#define EP_   (NE_ + NN) // with self loops

using short8  = __attribute__((ext_vector_type(8))) short;
using floatx4 = __attribute__((ext_vector_type(4))) float;

typedef __attribute__((address_space(3))) unsigned int lds_uint;
typedef const __attribute__((address_space(1))) unsigned int glb_uint;
#define ASYNC_LD16(g, l) __builtin_amdgcn_global_load_lds((glb_uint*)(g), (lds_uint*)(l), 16, 0, 0)

__device__ __forceinline__ float eluf(float x){ return x > 0.f ? x : expm1f(x); }
__device__ __forceinline__ float lrelu(float x){ return x > 0.f ? x : 0.2f * x; }
__device__ __forceinline__ float bf2f(unsigned short u){
    union { unsigned int i; float f; } c; c.i = ((unsigned int)u) << 16; return c.f;
}
__device__ __forceinline__ unsigned short f2b(float f){
    union { float f; unsigned int u; } c; c.f = f;
    unsigned int u = c.u;
    return (unsigned short)((u + 0x7FFFu + ((u >> 16) & 1u)) >> 16);   // RNE
}

// ---------------- CSR build ----------------
__global__ void k_zero_i(int* __restrict__ p, int n){
    int i = blockIdx.x * 256 + threadIdx.x;
    if (i < n) p[i] = 0;
}

__global__ void k_degree(const int* __restrict__ ei, int* __restrict__ deg){
    int i = blockIdx.x * 256 + threadIdx.x;
    if (i >= EP_) return;
    int d = (i < NE_) ? ei[NE_ + i] : (i - NE_);
    atomicAdd(&deg[d], 1);
}

__global__ __launch_bounds__(1024) void k_scan(const int* __restrict__ deg, int* __restrict__ offs){
    __shared__ int s[1024];
    int tid  = threadIdx.x;
    int base = tid * 16;
    int local[16];
    int sum = 0;
    #pragma unroll
    for (int i = 0; i < 16; i++){ local[i] = deg[base + i]; sum += local[i]; }
    s[tid] = sum;
    __syncthreads();
    for (int off = 1; off < 1024; off <<= 1){
        int v = (tid >= off) ? s[tid - off] : 0;
        __syncthreads();
        s[tid] += v;
        __syncthreads();
    }
    int run = (tid == 0) ? 0 : s[tid - 1];
    #pragma unroll
    for (int i = 0; i < 16; i++){ offs[base + i] = run; run += local[i]; }
    if (tid == 1023) offs[NN] = run;
}

__global__ void k_scatter(const int* __restrict__ ei, const int* __restrict__ offs,
                          int* __restrict__ cursor, int* __restrict__ csr){
    int i = blockIdx.x * 256 + threadIdx.x;
    if (i >= EP_) return;
    int srcv, dstv;
    if (i < NE_){ srcv = ei[i]; dstv = ei[NE_ + i]; }
    else        { srcv = dstv = i - NE_; }
    int pos = offs[dstv] + atomicAdd(&cursor[dstv], 1);
    csr[pos] = srcv;
}

// ---------------- merged casts: x -> bf16 ; W1,W2 -> bf16 transposed ----------------
__global__ __launch_bounds__(256) void k_casts(const float* __restrict__ x, ushort* __restrict__ xb,
    const float* __restrict__ W1, ushort* __restrict__ W1T,
    const float* __restrict__ W2, ushort* __restrict__ W2T){
    int bid = blockIdx.x, tid = threadIdx.x;
    if (bid < 16384){
        int i = bid * 256 + tid;
        float4 v = *(const float4*)(x + (size_t)i * 4);
        ushort4 o = { f2b(v.x), f2b(v.y), f2b(v.z), f2b(v.w) };
        *(ushort4*)(xb + (size_t)i * 4) = o;
    } else if (bid < 16384 + 512){
        int t = (bid - 16384) * 256 + tid;          // W1: 1024x512 -> T
        int n = t >> 8, kb = (t & 255) * 4;
        ushort4 o = { f2b(W1[(size_t)(kb+0)*HCdim + n]), f2b(W1[(size_t)(kb+1)*HCdim + n]),
                      f2b(W1[(size_t)(kb+2)*HCdim + n]), f2b(W1[(size_t)(kb+3)*HCdim + n]) };
        *(ushort4*)(W1T + (size_t)n * DIN + kb) = o;
    } else {
        int t = (bid - 16896) * 256 + tid;          // W2: 512x512 -> T
        int n = t >> 7, kb = (t & 127) * 4;
        ushort4 o = { f2b(W2[(size_t)(kb+0)*HCdim + n]), f2b(W2[(size_t)(kb+1)*HCdim + n]),
                      f2b(W2[(size_t)(kb+2)*HCdim + n]), f2b(W2[(size_t)(kb+3)*HCdim + n]) };
        *(ushort4*)(W2T + (size_t)n * HCdim + kb) = o;
    }
}

// ---------------- bf16 MFMA GEMM + fused attention-scalar epilogue ----------------
__global__ __launch_bounds__(256) void gemm_bf16(const ushort* __restrict__ A,
                                                 const ushort* __restrict__ BT,
                                                 ushort* __restrict__ C,
                                                 const float* __restrict__ att_s,
                                                 const float* __restrict__ att_d,
                                                 float* __restrict__ as_, float* __restrict__ ad_,
                                                 int M, int Nn, int K){
    __shared__ ushort As[128 * 32];
    __shared__ ushort Bs[128 * 32];
    __shared__ float prS[2][128];
    __shared__ float prD[2][128];
    int tid = threadIdx.x;
    int m0 = blockIdx.y * 128, n0 = blockIdx.x * 128;
    int cx = blockIdx.x;                 // head
    int lane = tid & 63, w = tid >> 6;
    int wm = (w >> 1) * 64, wn = (w & 1) * 64;
    int la = lane & 15, qd = lane >> 4;

    int srow = tid >> 2, schunk = (tid & 3) * 8;
    const ushort* Ag = A  + (size_t)(m0 + srow) * K + schunk;
    const ushort* Bg = BT + (size_t)(n0 + srow) * K + schunk;
    ushort* Asw = &As[srow * 32 + schunk];
    ushort* Bsw = &Bs[srow * 32 + schunk];

    floatx4 acc[4][4] = {};
    for (int k0 = 0; k0 < K; k0 += 32){
        __syncthreads();
        ASYNC_LD16(Ag + k0,                  Asw);
        ASYNC_LD16(Ag + (size_t)64 * K + k0, Asw + 64 * 32);
        ASYNC_LD16(Bg + k0,                  Bsw);
        ASYNC_LD16(Bg + (size_t)64 * K + k0, Bsw + 64 * 32);
        __syncthreads();
        short8 af[4], bf[4];
        #pragma unroll
        for (int i = 0; i < 4; i++){
            af[i] = *(const short8*)&As[(wm + i*16 + la) * 32 + qd * 8];
            bf[i] = *(const short8*)&Bs[(wn + i*16 + la) * 32 + qd * 8];
        }
        #pragma unroll
        for (int i = 0; i < 4; i++)
            #pragma unroll
            for (int j = 0; j < 4; j++)
                acc[i][j] = __builtin_amdgcn_mfma_f32_16x16x32_bf16(af[i], bf[j], acc[i][j], 0, 0, 0);
    }
    float asv[4], adv[4];
    #pragma unroll
    for (int j = 0; j < 4; j++){
        asv[j] = att_s[cx * 128 + wn + j * 16 + la];
        adv[j] = att_d[cx * 128 + wn + j * 16 + la];
    }
    int half = wn >> 6;
    #pragma unroll
    for (int i = 0; i < 4; i++){
        #pragma unroll
        for (int r = 0; r < 4; r++){
            float ps = 0.f, pd = 0.f;
            #pragma unroll
            for (int j = 0; j < 4; j++){
                ps = fmaf(acc[i][j][r], asv[j], ps);
                pd = fmaf(acc[i][j][r], adv[j], pd);
            }
            #pragma unroll
            for (int off = 1; off < 16; off <<= 1){
                ps += __shfl_xor(ps, off);
                pd += __shfl_xor(pd, off);
            }
            if (la == 0){
                int rl = wm + i * 16 + qd * 4 + r;
                prS[half][rl] = ps; prD[half][rl] = pd;
            }
        }
    }
    #pragma unroll
    for (int i = 0; i < 4; i++)
        #pragma unroll
        for (int j = 0; j < 4; j++){
            int col = n0 + wn + j * 16 + la;
            #pragma unroll
            for (int r = 0; r < 4; r++){
                int row = m0 + wm + i * 16 + qd * 4 + r;
                C[(size_t)row * Nn + col] = f2b(acc[i][j][r]);
            }
        }
    __syncthreads();
    if (tid < 128){
        as_[(size_t)(m0 + tid) * 4 + cx] = prS[0][tid] + prS[1][tid];
        ad_[(size_t)(m0 + tid) * 4 + cx] = prD[0][tid] + prD[1][tid];
    }
}

// ---------------- edge weights: wbuf[j][h] = bf16(exp(lrelu(as[src_j][h] + ad[dst_j][h]))) ----------------
__global__ __launch_bounds__(256) void k_edgew(const int* __restrict__ offs, const int* __restrict__ csr,
    const float* __restrict__ as_, const float* __restrict__ ad_, ushort* __restrict__ wbuf){
    int wv = threadIdx.x >> 6, lane = threadIdx.x & 63;
    int n = blockIdx.x * 4 + wv;
    int start = offs[n], end = offs[n + 1];
    float4 ad4 = *(const float4*)(ad_ + (size_t)n * 4);
    for (int j = start + lane; j < end; j += 64){
        int s = csr[j];
        float4 as4 = *(const float4*)(as_ + (size_t)s * 4);
        ushort4 o = { f2b(__expf(lrelu(as4.x + ad4.x))), f2b(__expf(lrelu(as4.y + ad4.y))),
                      f2b(__expf(lrelu(as4.z + ad4.z))), f2b(__expf(lrelu(as4.w + ad4.w))) };
        *(ushort4*)(wbuf + (size_t)j * 4) = o;
    }
}

// ---------------- aggregation: 2 waves per node (256 ch each), group-double-buffered depth-8 ----------------
// out[n] = elu((sum_j w_j*h[src_j]) / (sum_j w_j) + bias); w precomputed in wbuf.
// Loads: index CLAMPED (address-safe, tail rows L1-hot); validity ZERO-MASKED in the weight,
// so consumes are branch-free and can't double-count. Static register slots (no rotation).
template<bool POOL>
__global__ __launch_bounds__(256) void k_aggregate(const ushort* __restrict__ h,
    const int* __restrict__ offs, const int* __restrict__ csr,
    const ushort* __restrict__ wbuf,
    const float* __restrict__ bias, ushort* __restrict__ out,
    const float* __restrict__ pw, const float* __restrict__ pb, float* __restrict__ x2){
    __shared__ float pr[4];
    int wv   = threadIdx.x >> 6;        // 0..3 : two waves per node
    int lane = threadIdx.x & 63;
    int n    = blockIdx.x * 2 + (wv >> 1);
    int half = wv & 1;                  // channel half
    int cb   = half * 256 + lane * 4;   // this lane's 4 channels
    int head = cb >> 7;
    int start = offs[n], end = offs[n + 1];
    const ushort* hrow = h + cb;
    const ushort* wrow = wbuf + head;
    float dsum = 0.f;
    float a0 = 0.f, a1 = 0.f, a2 = 0.f, a3 = 0.f;

    for (int base = start; base < end; base += 64){
        int cnt = min(64, end - base);
        int pre = csr[base + min(lane, cnt - 1)];   // batch indices staged in regs
        float wa0, wa1, wa2, wa3, wb0, wb1, wb2, wb3;
        uint2 ha0, ha1, ha2, ha3, hb0, hb1, hb2, hb3;

#define LOADE(W, H, E)                                                        \
        { int e_ = (E); int ec_ = min(e_, cnt - 1);                           \
          int s_ = __builtin_amdgcn_readlane(pre, ec_);                       \
          float wv_ = bf2f(wrow[(size_t)(base + ec_) * 4]);                   \
          W = (e_ < cnt) ? wv_ : 0.f;                                         \
          H = *(const uint2*)(hrow + (size_t)s_ * HCdim); }

#define CONS(W, H)                                                            \
        { dsum += W;                                                          \
          a0 = fmaf(W, bf2f(H.x & 0xffff), a0);                               \
          a1 = fmaf(W, bf2f(H.x >> 16),    a1);                               \
          a2 = fmaf(W, bf2f(H.y & 0xffff), a2);                               \
          a3 = fmaf(W, bf2f(H.y >> 16),    a3); }

        LOADE(wa0, ha0, 0) LOADE(wa1, ha1, 1) LOADE(wa2, ha2, 2) LOADE(wa3, ha3, 3)
        for (int g = 0; g < cnt; g += 8){
            LOADE(wb0, hb0, g + 4) LOADE(wb1, hb1, g + 5)
            LOADE(wb2, hb2, g + 6) LOADE(wb3, hb3, g + 7)
            CONS(wa0, ha0) CONS(wa1, ha1) CONS(wa2, ha2) CONS(wa3, ha3)
            LOADE(wa0, ha0, g + 8) LOADE(wa1, ha1, g + 9)
            LOADE(wa2, ha2, g + 10) LOADE(wa3, ha3, g + 11)
            CONS(wb0, hb0) CONS(wb1, hb1) CONS(wb2, hb2) CONS(wb3, hb3)
        }
#undef LOADE
#undef CONS
    }
    float rden = 1.f / (dsum + 1e-16f);
    float4 b4 = *(const float4*)(bias + cb);
    float e0 = eluf(fmaf(a0, rden, b4.x));
    float e1 = eluf(fmaf(a1, rden, b4.y));
    float e2 = eluf(fmaf(a2, rden, b4.z));
    float e3 = eluf(fmaf(a3, rden, b4.w));
    uint2 o;
    o.x = (unsigned)f2b(e0) | ((unsigned)f2b(e1) << 16);
    o.y = (unsigned)f2b(e2) | ((unsigned)f2b(e3) << 16);
    *(uint2*)(out + (size_t)n * HCdim + cb) = o;
    if (POOL){
        float4 w4 = *(const float4*)(pw + cb);
        float s = e0 * w4.x + e1 * w4.y + e2 * w4.z + e3 * w4.w;
        #pragma unroll
        for (int off = 32; off; off >>= 1) s += __shfl_down(s, off);
        if (lane == 0) pr[wv] = s;
        __syncthreads();
        if (half == 0 && lane == 0) x2[n] = pr[wv] + pr[wv + 1] + pb[0];
    }
}

// ---------------- fc1 with fused layernorm ----------------
__global__ __launch_bounds__(256) void k_fc1_ln(const float* __restrict__ x2,
    const float* __restrict__ lng, const float* __restrict__ lnb,
    const float* __restrict__ W, const float* __restrict__ bias,
    float* __restrict__ outms, float* __restrict__ e1b){
    __shared__ float xs[1024];
    __shared__ float red[4][64];
    __shared__ float red2[8];
    __shared__ float stats[2];
    int tid = threadIdx.x;
    int b = blockIdx.y, c0 = blockIdx.x * 64;
    float4 v = *(const float4*)(x2 + b * 1024 + tid * 4);
    float s  = v.x + v.y + v.z + v.w;
    float sq = v.x * v.x + v.y * v.y + v.z * v.z + v.w * v.w;
    #pragma unroll
    for (int off = 32; off; off >>= 1){ s += __shfl_down(s, off); sq += __shfl_down(sq, off); }
    if ((tid & 63) == 0){ red2[(tid >> 6) * 2] = s; red2[(tid >> 6) * 2 + 1] = sq; }
    __syncthreads();
    if (tid == 0){
        float S  = red2[0] + red2[2] + red2[4] + red2[6];
        float SQ = red2[1] + red2[3] + red2[5] + red2[7];
        float mu  = S * (1.f / 1024.f);
        float var = SQ * (1.f / 1024.f) - mu * mu;
        stats[0] = mu; stats[1] = rsqrtf(var + 1e-5f);
    }
    __syncthreads();
    float mu = stats[0], r = stats[1];
    float4 g4  = *(const float4*)(lng + tid * 4);
    float4 bb4 = *(const float4*)(lnb + tid * 4);
    float4 o;
    o.x = (v.x - mu) * r * g4.x + bb4.x;
    o.y = (v.y - mu) * r * g4.y + bb4.y;
    o.z = (v.z - mu) * r * g4.z + bb4.z;
    o.w = (v.w - mu) * r * g4.w + bb4.w;
    *(float4*)&xs[tid * 4] = o;
    if (blockIdx.x == 0) *(float4*)(outms + b * 1024 + tid * 4) = o;
    __syncthreads();
    int tx = tid & 63, ty = tid >> 6;
    const float* wp = W + (size_t)(ty * 256) * 512 + c0 + tx;
    float a = 0.f;
    #pragma unroll 8
    for (int i = 0; i < 256; i++)
        a = fmaf(xs[ty * 256 + i], wp[(size_t)i * 512], a);
    red[ty][tx] = a;
    __syncthreads();
    if (ty == 0){
        float vv = red[0][tx] + red[1][tx] + red[2][tx] + red[3][tx] + bias[c0 + tx];
        e1b[b * 512 + c0 + tx] = eluf(vv);
    }
}

// ---------------- FC layer ----------------
template<int K, int NOUT>
__global__ __launch_bounds__(256) void k_fc(const float* __restrict__ in,
    const float* __restrict__ W, const float* __restrict__ bias, float* __restrict__ outb){
    __shared__ float xs[K];
    __shared__ float red[4][64];
    int tid = threadIdx.x;
    int b = blockIdx.y, c0 = blockIdx.x * 64;
    int tx = tid & 63, ty = tid >> 6;
    for (int i = tid * 4; i < K; i += 1024)
        *(float4*)&xs[i] = *(const float4*)(in + b * K + i);
    __syncthreads();
    const float* wp = W + (size_t)(ty * (K / 4)) * NOUT + c0 + tx;
    float a = 0.f;
    #pragma unroll 8
    for (int i = 0; i < K / 4; i++)
        a = fmaf(xs[ty * (K / 4) + i], wp[(size_t)i * NOUT], a);
    red[ty][tx] = a;
    __syncthreads();
    if (ty == 0){
        float v = red[0][tx] + red[1][tx] + red[2][tx] + red[3][tx] + bias[c0 + tx];
        outb[b * NOUT + tx + c0] = eluf(v);
    }
}

// ---------------- final FC (128->64) + e output + pred ----------------
__global__ __launch_bounds__(256) void k_fc_final(const float* __restrict__ in,
    const float* __restrict__ W, const float* __restrict__ bias,
    const float* __restrict__ lw, const float* __restrict__ lb, float* __restrict__ out){
    __shared__ float xs[128];
    __shared__ float red[4][64];
    __shared__ float evs[64];
    int tid = threadIdx.x;
    int b = blockIdx.x;
    int tx = tid & 63, ty = tid >> 6;
    if (tid * 4 < 128)
        *(float4*)&xs[tid * 4] = *(const float4*)(in + b * 128 + tid * 4);
    __syncthreads();
    const float* wp = W + (size_t)(ty * 32) * 64 + tx;
    float a = 0.f;
    #pragma unroll
    for (int i = 0; i < 32; i++)
        a = fmaf(xs[ty * 32 + i], wp[(size_t)i * 64], a);
    red[ty][tx] = a;
    __syncthreads();
    if (ty == 0){
        float ev = eluf(red[0][tx] + red[1][tx] + red[2][tx] + red[3][tx] + bias[tx]);
        evs[tx] = ev;
        out[16384 + b * 64 + tx] = ev;
    }
    __syncthreads();
    if (ty == 0){
        float p = evs[tx] * lw[tx];
        #pragma unroll
        for (int off = 32; off; off >>= 1) p += __shfl_down(p, off);
        if (tx == 0) out[16384 + 1024 + b] = p + lb[0];
    }
}

extern "C" void kernel_launch(void* const* d_in, const int* in_sizes, int n_in,
                              void* d_out, int out_size, void* d_ws, size_t ws_size,
                              hipStream_t stream) {
    const float* x        = (const float*)d_in[0];
    const int*   ei       = (const int*)  d_in[1];
    const float* W1       = (const float*)d_in[3];
    const float* att_src1 = (const float*)d_in[4];
    const float* att_dst1 = (const float*)d_in[5];
    const float* b1       = (const float*)d_in[6];
    const float* W2       = (const float*)d_in[7];
    const float* att_src2 = (const float*)d_in[8];
    const float* att_dst2 = (const float*)d_in[9];
    const float* b2       = (const float*)d_in[10];
    const float* p2w      = (const float*)d_in[13];
    const float* p2b      = (const float*)d_in[14];
    const float* ln_g     = (const float*)d_in[15];
    const float* ln_b     = (const float*)d_in[16];
    const float* fw1      = (const float*)d_in[17];
    const float* fb1      = (const float*)d_in[18];
    const float* fw2      = (const float*)d_in[19];
    const float* fb2      = (const float*)d_in[20];
    const float* fw3      = (const float*)d_in[21];
    const float* fb3      = (const float*)d_in[22];
    const float* fw4      = (const float*)d_in[23];
    const float* fb4      = (const float*)d_in[24];
    const float* lw       = (const float*)d_in[25];
    const float* lb       = (const float*)d_in[26];
    float* out = (float*)d_out;

    // workspace layout (bytes), ~56.1 MB total
    char* w = (char*)d_ws;
    ushort* xb   = (ushort*)(w);
    ushort* h1b  = (ushort*)(w);
    ushort* h2b  = (ushort*)(w + 16777216);
    ushort* hpre = (ushort*)(w + 33554432);
    ushort* W1T  = (ushort*)(w + 50331648);
    ushort* W2T  = (ushort*)(w + 51380224);
    float* asb   = (float*)(w + 51904512);
    float* adb   = (float*)(w + 52166656);
    int*   deg   = (int*)  (w + 52428800);
    int*   cursor= (int*)  (w + 52494336);
    int*   offs  = (int*)  (w + 52559872);
    int*   csr   = (int*)  (w + 52625664);
    ushort* wbuf = (ushort*)(w + 53739776);
    float* x2b   = (float*)(w + 55968000);
    float* e1b   = (float*)(w + 56033536);
    float* e2b   = (float*)(w + 56066304);
    float* e3b   = (float*)(w + 56082688);

    // ---- CSR build ----
    k_zero_i <<<(2 * NN + 255) / 256, 256, 0, stream>>>(deg, 2 * NN);
    k_degree <<<(EP_ + 255) / 256, 256, 0, stream>>>(ei, deg);
    k_scan   <<<1, 1024, 0, stream>>>(deg, offs);
    k_scatter<<<(EP_ + 255) / 256, 256, 0, stream>>>(ei, offs, cursor, csr);

    // ---- casts (merged) ----
    k_casts<<<16384 + 512 + 256, 256, 0, stream>>>(x, xb, W1, W1T, W2, W2T);

    dim3 ggrid(HCdim / 128, NN / 128);
    // ---- GAT layer 1 ----
    gemm_bf16         <<<ggrid, 256, 0, stream>>>(xb, W1T, hpre, att_src1, att_dst1,
                                                  asb, adb, NN, HCdim, DIN);
    k_edgew           <<<NN / 4, 256, 0, stream>>>(offs, csr, asb, adb, wbuf);
    k_aggregate<false><<<NN / 2, 256, 0, stream>>>(hpre, offs, csr, wbuf, b1, h1b,
                                                   nullptr, nullptr, nullptr);
    // ---- GAT layer 2 (pool fused) ----
    gemm_bf16         <<<ggrid, 256, 0, stream>>>(h1b, W2T, hpre, att_src2, att_dst2,
                                                  asb, adb, NN, HCdim, HCdim);
    k_edgew           <<<NN / 4, 256, 0, stream>>>(offs, csr, asb, adb, wbuf);
    k_aggregate<true> <<<NN / 2, 256, 0, stream>>>(hpre, offs, csr, wbuf, b2, h2b,
                                                   p2w, p2b, x2b);
    // ---- encoder MLP (LN fused into fc1) ----
    k_fc1_ln          <<<dim3(8, 16), 256, 0, stream>>>(x2b, ln_g, ln_b, fw1, fb1, out, e1b);
    k_fc< 512, 256>   <<<dim3(4, 16), 256, 0, stream>>>(e1b, fw2, fb2, e2b);
    k_fc< 256, 128>   <<<dim3(2, 16), 256, 0, stream>>>(e2b, fw3, fb3, e3b);
    k_fc_final        <<<16, 256, 0, stream>>>(e3b, fw4, fb4, lw, lb, out);
}